// Round 2
// baseline (225.782 us; speedup 1.0000x reference)
//
#include <hip/hip_runtime.h>
#include <hip/hip_bf16.h>
#include <cstdint>
#include <cstddef>

#define DEVI static __device__ __forceinline__

typedef short s16x8 __attribute__((ext_vector_type(8)));
typedef float f32x4 __attribute__((ext_vector_type(4)));

DEVI f32x4 mfma16x16(s16x8 a, s16x8 b, f32x4 c) {
  return __builtin_amdgcn_mfma_f32_16x16x32_bf16(a, b, c, 0, 0, 0);
}

// fp32 -> bf16 round-to-nearest-even
DEVI unsigned short f2bf(float f) {
  unsigned u = __builtin_bit_cast(unsigned, f);
  u += 0x7FFFu + ((u >> 16) & 1u);
  return (unsigned short)(u >> 16);
}

DEVI s16x8 ld8(const unsigned short* p) { return *(const s16x8*)p; }

// ---------------------------------------------------------------------------
// fp32 -> bf16 bulk convert (memory-bound, ~8B/lane loads + 16B stores)
// ---------------------------------------------------------------------------
__global__ __launch_bounds__(256) void cvt_bf16(
    const float* __restrict__ src, unsigned short* __restrict__ dst, int n8) {
  int i = blockIdx.x * 256 + threadIdx.x;
  if (i >= n8) return;
  const float4* s = (const float4*)src + (size_t)i * 2;
  float4 a = s[0], b = s[1];
  s16x8 r;
  r[0] = (short)f2bf(a.x); r[1] = (short)f2bf(a.y);
  r[2] = (short)f2bf(a.z); r[3] = (short)f2bf(a.w);
  r[4] = (short)f2bf(b.x); r[5] = (short)f2bf(b.y);
  r[6] = (short)f2bf(b.z); r[7] = (short)f2bf(b.w);
  *(s16x8*)(dst + (size_t)i * 8) = r;
}

// ---------------------------------------------------------------------------
// C[m][n] = sum_k A[m][k] * B[n][k]   (NT GEMM, all-bf16 inputs, fp32 acc)
// EPI==0: Cf fp32 [M][N].
// EPI==2: fused qkv split + RoPE epilogue (M=4096, N=3072):
//         cols [0,1024) -> Q (rope, *0.125) -> Qp[bh][s][64]
//         cols [1024,2048) -> K (rope)      -> Kp[bh][s][64]
//         cols [2048,3072) -> V             -> Vp[bh][64][2048] (transposed)
// 128x128x64 tiles, 256 threads (2x2 waves of 64x64), reg-staged LDS with
// T2 XOR swizzle (elem ^= (row&7)<<3) -> conflict-free ds_read_b128.
// ---------------------------------------------------------------------------
template <int EPI>
__global__ __launch_bounds__(256, 2) void gemm_nt(
    const unsigned short* __restrict__ A, const unsigned short* __restrict__ B,
    float* __restrict__ Cf, unsigned short* __restrict__ Qp,
    unsigned short* __restrict__ Kp, unsigned short* __restrict__ Vp,
    int M, int N, int K) {
  __shared__ __align__(16) unsigned short As[128 * 64];
  __shared__ __align__(16) unsigned short Bs[128 * 64];
  const int tid = threadIdx.x;
  const int m0 = blockIdx.y * 128, n0 = blockIdx.x * 128;
  const int wid = tid >> 6, lane = tid & 63;
  const int wm = wid >> 1, wn = wid & 1;
  const int lr = lane & 15, lg = lane >> 4;

  f32x4 acc[4][4] = {};
  const int T = K >> 6;
  s16x8 pa[4], pb[4];

  #pragma unroll
  for (int j = 0; j < 4; ++j) {
    int c = tid + j * 256, row = c >> 3, cc = c & 7;
    pa[j] = ld8(A + (size_t)(m0 + row) * K + cc * 8);
    pb[j] = ld8(B + (size_t)(n0 + row) * K + cc * 8);
  }

  for (int t = 0; t < T; ++t) {
    __syncthreads();
    #pragma unroll
    for (int j = 0; j < 4; ++j) {
      int c = tid + j * 256, row = c >> 3, cc = c & 7;
      int le = row * 64 + ((cc * 8) ^ ((row & 7) << 3));
      *(s16x8*)&As[le] = pa[j];
      *(s16x8*)&Bs[le] = pb[j];
    }
    __syncthreads();
    if (t + 1 < T) {
      const int k0 = (t + 1) << 6;
      #pragma unroll
      for (int j = 0; j < 4; ++j) {
        int c = tid + j * 256, row = c >> 3, cc = c & 7;
        pa[j] = ld8(A + (size_t)(m0 + row) * K + k0 + cc * 8);
        pb[j] = ld8(B + (size_t)(n0 + row) * K + k0 + cc * 8);
      }
    }
    s16x8 af[4][2], bf[4][2];
    #pragma unroll
    for (int m = 0; m < 4; ++m)
      #pragma unroll
      for (int kk = 0; kk < 2; ++kk) {
        int row = wm * 64 + m * 16 + lr;
        af[m][kk] = *(const s16x8*)&As[row * 64 + ((kk * 32 + lg * 8) ^ ((row & 7) << 3))];
      }
    #pragma unroll
    for (int n = 0; n < 4; ++n)
      #pragma unroll
      for (int kk = 0; kk < 2; ++kk) {
        int row = wn * 64 + n * 16 + lr;
        bf[n][kk] = *(const s16x8*)&Bs[row * 64 + ((kk * 32 + lg * 8) ^ ((row & 7) << 3))];
      }
    #pragma unroll
    for (int kk = 0; kk < 2; ++kk)
      #pragma unroll
      for (int m = 0; m < 4; ++m)
        #pragma unroll
        for (int n = 0; n < 4; ++n)
          acc[m][n] = mfma16x16(af[m][kk], bf[n][kk], acc[m][n]);
  }

  // epilogue  (C/D layout: row = lg*4 + i, col = lr)
  if constexpr (EPI == 0) {
    #pragma unroll
    for (int m = 0; m < 4; ++m)
      #pragma unroll
      for (int i = 0; i < 4; ++i) {
        int r = m0 + wm * 64 + m * 16 + lg * 4 + i;
        #pragma unroll
        for (int n = 0; n < 4; ++n)
          Cf[(size_t)r * N + n0 + wn * 64 + n * 16 + lr] = acc[m][n][i];
      }
  } else {
    const int colb = n0 + wn * 64;          // wave's 64-col span = one head
    const int part = colb >> 10;            // 0=q 1=k 2=v (block-uniform)
    const int h = (colb & 1023) >> 6;
    #pragma unroll
    for (int m = 0; m < 4; ++m)
      #pragma unroll
      for (int i = 0; i < 4; ++i) {
        const int r = m0 + wm * 64 + m * 16 + lg * 4 + i;
        const int b = r >> 11, s = r & 2047;
        const size_t bh = (size_t)b * 16 + h;
        if (part == 2) {
          #pragma unroll
          for (int n = 0; n < 4; ++n)
            Vp[(bh * 64 + n * 16 + lr) * 2048 + s] = f2bf(acc[m][n][i]);
        } else {
          #pragma unroll
          for (int n = 0; n < 2; ++n) {
            const int d = n * 16 + lr;      // 0..31; pair (d, d+32) in-lane
            float ang = (float)s * exp2f((float)d * -0.4152410118609203f);
            float c, sn;
            sincosf(ang, &sn, &c);
            float x1 = acc[m][n][i], x2 = acc[m][n + 2][i];
            float o1 = x1 * c - x2 * sn;
            float o2 = x2 * c + x1 * sn;
            unsigned short* dst;
            if (part == 0) { o1 *= 0.125f; o2 *= 0.125f; dst = Qp; }
            else dst = Kp;
            dst[(bh * 2048 + s) * 64 + d] = f2bf(o1);
            dst[(bh * 2048 + s) * 64 + d + 32] = f2bf(o2);
          }
        }
      }
  }
}

// ---------------------------------------------------------------------------
// Causal flash attention — barrier-free, one wave per block.
// Qr/Kr: bf16 [BH][S][64] (Q pre-scaled by 1/8), VT: bf16 [BH][64][S],
// Z: bf16 [B*S][1024].  Each wave owns 32 q-rows; K/V fragments are read
// directly from L2 (no LDS staging, no __syncthreads); only P round-trips
// through a private 4KB LDS buffer.  2048 blocks -> all waves co-resident.
// ---------------------------------------------------------------------------
__global__ __launch_bounds__(64, 2) void attn_fwd(
    const unsigned short* __restrict__ Qr, const unsigned short* __restrict__ Kr,
    const unsigned short* __restrict__ VT, unsigned short* __restrict__ Z) {
  __shared__ __align__(16) unsigned short Pl[32 * 64];
  const int lane = threadIdx.x;
  const int bid = blockIdx.x;
  const int bh = bid >> 6;                 // 64 consecutive blocks share (b,h) KV
  const int qc = 63 - (bid & 63);          // heavy q-chunks first
  const int b = bh >> 4, h = bh & 15;
  const int qw = qc << 5;                  // first q row of this wave
  const int lr = lane & 15, lg = lane >> 4;

  const unsigned short* Qb = Qr + ((size_t)bh << 17);
  const unsigned short* Kb = Kr + ((size_t)bh << 17);
  const unsigned short* Vb = VT + ((size_t)bh << 17);

  s16x8 qf[2][2];
  #pragma unroll
  for (int m = 0; m < 2; ++m)
    #pragma unroll
    for (int kk = 0; kk < 2; ++kk)
      qf[m][kk] = ld8(Qb + (size_t)(qw + m * 16 + lr) * 64 + kk * 32 + lg * 8);

  f32x4 oacc[2][4] = {};
  float mrun[8], lrun[8];
  #pragma unroll
  for (int r = 0; r < 8; ++r) { mrun[r] = -__builtin_inff(); lrun[r] = 0.f; }

  const int nt = (qw >> 6) + 1;
  for (int t = 0; t < nt; ++t) {
    const int kv0 = t << 6;

    // K fragments straight from L2
    s16x8 kf[2][4];
    #pragma unroll
    for (int kk = 0; kk < 2; ++kk)
      #pragma unroll
      for (int n = 0; n < 4; ++n)
        kf[kk][n] = ld8(Kb + (size_t)(kv0 + n * 16 + lr) * 64 + kk * 32 + lg * 8);

    f32x4 sacc[2][4] = {};
    #pragma unroll
    for (int kk = 0; kk < 2; ++kk)
      #pragma unroll
      for (int m = 0; m < 2; ++m)
        #pragma unroll
        for (int n = 0; n < 4; ++n)
          sacc[m][n] = mfma16x16(qf[m][kk], kf[kk][n], sacc[m][n]);

    // V fragments issued now so L2 latency hides under softmax (T14-lite)
    s16x8 vf[2][4];
    #pragma unroll
    for (int kk = 0; kk < 2; ++kk)
      #pragma unroll
      for (int n = 0; n < 4; ++n)
        vf[kk][n] = ld8(Vb + (size_t)(n * 16 + lr) * 2048 + kv0 + kk * 32 + lg * 8);

    // online softmax; each lane owns 8 rows (m*4+i), 4 cols each
    const bool diag = (kv0 + 63) > qw;
    #pragma unroll
    for (int m = 0; m < 2; ++m)
      #pragma unroll
      for (int i = 0; i < 4; ++i) {
        const int ridx = m * 4 + i;
        const int row = m * 16 + lg * 4 + i;   // local q row 0..31
        const int qabs = qw + row;
        float sv[4];
        float mx = -__builtin_inff();
        #pragma unroll
        for (int n = 0; n < 4; ++n) {
          float v = sacc[m][n][i];
          if (diag && (kv0 + n * 16 + lr) > qabs) v = -__builtin_inff();
          sv[n] = v;
          mx = fmaxf(mx, v);
        }
        mx = fmaxf(mx, __shfl_xor(mx, 1));
        mx = fmaxf(mx, __shfl_xor(mx, 2));
        mx = fmaxf(mx, __shfl_xor(mx, 4));
        mx = fmaxf(mx, __shfl_xor(mx, 8));
        const float mnew = fmaxf(mrun[ridx], mx);
        const float alpha = __expf(mrun[ridx] - mnew);
        float rs = 0.f;
        #pragma unroll
        for (int n = 0; n < 4; ++n) {
          const float p = __expf(sv[n] - mnew);
          rs += p;
          Pl[row * 64 + ((n * 16 + lr) ^ ((row & 7) << 3))] = (short)f2bf(p);
        }
        rs += __shfl_xor(rs, 1);
        rs += __shfl_xor(rs, 2);
        rs += __shfl_xor(rs, 4);
        rs += __shfl_xor(rs, 8);
        lrun[ridx] = lrun[ridx] * alpha + rs;
        mrun[ridx] = mnew;
        #pragma unroll
        for (int n = 0; n < 4; ++n) oacc[m][n][i] *= alpha;
      }

    // own-wave P writes must land before fragment reads (rule 18)
    asm volatile("s_waitcnt lgkmcnt(0)" ::: "memory");
    __builtin_amdgcn_sched_barrier(0);

    // O += P V
    #pragma unroll
    for (int kk = 0; kk < 2; ++kk) {
      s16x8 pf[2];
      #pragma unroll
      for (int m = 0; m < 2; ++m) {
        const int row = m * 16 + lr;
        pf[m] = *(const s16x8*)&Pl[row * 64 + ((kk * 32 + lg * 8) ^ ((row & 7) << 3))];
      }
      #pragma unroll
      for (int m = 0; m < 2; ++m)
        #pragma unroll
        for (int n = 0; n < 4; ++n)
          oacc[m][n] = mfma16x16(pf[m], vf[kk][n], oacc[m][n]);
    }
  }

  // normalize + write Z[b*S+q][h*64+d] bf16
  #pragma unroll
  for (int m = 0; m < 2; ++m)
    #pragma unroll
    for (int i = 0; i < 4; ++i) {
      const float inv = 1.f / lrun[m * 4 + i];
      const int q = qw + m * 16 + lg * 4 + i;
      const size_t base = ((size_t)b * 2048 + q) * 1024 + h * 64;
      #pragma unroll
      for (int n = 0; n < 4; ++n)
        Z[base + n * 16 + lr] = (short)f2bf(oacc[m][n][i] * inv);
    }
}

// ---------------------------------------------------------------------------
extern "C" void kernel_launch(void* const* d_in, const int* in_sizes, int n_in,
                              void* d_out, int out_size, void* d_ws, size_t ws_size,
                              hipStream_t stream) {
  const float* x     = (const float*)d_in[0];   // [2,2048,1024]
  const float* w_qkv = (const float*)d_in[1];   // [3072,1024]
  const float* w_o   = (const float*)d_in[2];   // [1024,1024]
  float* out = (float*)d_out;                   // [2,2048,1024] fp32

  unsigned short* wsp = (unsigned short*)d_ws;
  unsigned short* Qr  = wsp;                    // [32][2048][64] bf16  (8 MB)
  unsigned short* Kr  = wsp + 4194304;          // [32][2048][64] bf16  (8 MB)
  unsigned short* VT  = wsp + 8388608;          // [32][64][2048] bf16  (8 MB)
  unsigned short* Xb  = wsp + 12582912;         // [4096][1024]  bf16   (8 MB)
  unsigned short* Z   = Xb;                     // aliases Xb (disjoint lifetime)
  unsigned short* Wb  = wsp + 16777216;         // [3072][1024]  bf16   (6 MB)
  unsigned short* Wob = wsp + 19922944;         // [1024][1024]  bf16   (2 MB)
  // total ws use: 40 MiB

  // 0) one-time fp32 -> bf16 conversions (memory-bound)
  cvt_bf16<<<2048, 256, 0, stream>>>(x, Xb, 524288);
  cvt_bf16<<<1536, 256, 0, stream>>>(w_qkv, Wb, 393216);
  cvt_bf16<<<512, 256, 0, stream>>>(w_o, Wob, 131072);

  // 1) QKV projection + fused RoPE/split/transpose epilogue
  gemm_nt<2><<<dim3(24, 32), 256, 0, stream>>>(
      Xb, Wb, nullptr, Qr, Kr, VT, 4096, 3072, 1024);

  // 2) causal flash attention (barrier-free, 1 wave/block)
  attn_fwd<<<2048, 64, 0, stream>>>(Qr, Kr, VT, Z);

  // 3) output projection (fp32 out)
  gemm_nt<0><<<dim3(8, 32), 256, 0, stream>>>(
      Z, Wob, out, nullptr, nullptr, nullptr, 4096, 1024, 1024);
}

// Round 3
// 148.764 us; speedup vs baseline: 1.5177x; 1.5177x over previous
//
#include <hip/hip_runtime.h>
#include <hip/hip_bf16.h>
#include <cstdint>
#include <cstddef>

#define DEVI static __device__ __forceinline__

typedef short s16x8 __attribute__((ext_vector_type(8)));
typedef float f32x4 __attribute__((ext_vector_type(4)));

DEVI f32x4 mfma16x16(s16x8 a, s16x8 b, f32x4 c) {
  return __builtin_amdgcn_mfma_f32_16x16x32_bf16(a, b, c, 0, 0, 0);
}

// fp32 -> bf16 round-to-nearest-even
DEVI unsigned short f2bf(float f) {
  unsigned u = __builtin_bit_cast(unsigned, f);
  u += 0x7FFFu + ((u >> 16) & 1u);
  return (unsigned short)(u >> 16);
}

DEVI s16x8 ld8(const unsigned short* p) { return *(const s16x8*)p; }

// ---------------------------------------------------------------------------
// fp32 -> bf16 bulk convert (memory-bound)
// ---------------------------------------------------------------------------
__global__ __launch_bounds__(256) void cvt_bf16(
    const float* __restrict__ src, unsigned short* __restrict__ dst, int n8) {
  int i = blockIdx.x * 256 + threadIdx.x;
  if (i >= n8) return;
  const float4* s = (const float4*)src + (size_t)i * 2;
  float4 a = s[0], b = s[1];
  s16x8 r;
  r[0] = (short)f2bf(a.x); r[1] = (short)f2bf(a.y);
  r[2] = (short)f2bf(a.z); r[3] = (short)f2bf(a.w);
  r[4] = (short)f2bf(b.x); r[5] = (short)f2bf(b.y);
  r[6] = (short)f2bf(b.z); r[7] = (short)f2bf(b.w);
  *(s16x8*)(dst + (size_t)i * 8) = r;
}

// ---------------------------------------------------------------------------
// C[m][n] = sum_k A[m][k] * B[n][k]   (NT GEMM, all-bf16 inputs, fp32 acc)
// EPI==0: Cf fp32 [M][N].
// EPI==2: fused qkv split + RoPE epilogue (M=4096, N=3072):
//         cols [0,1024) -> Q (rope, *0.125*log2e) -> Qp[bh][s][64]
//         cols [1024,2048) -> K (rope)            -> Kp[bh][s][64]
//         cols [2048,3072) -> V                   -> Vp[bh][64][2048] (transposed)
// 128x128x64 tiles, 256 threads (2x2 waves of 64x64), reg-staged LDS with
// T2 XOR swizzle (elem ^= (row&7)<<3) -> conflict-free ds_read_b128.
// ---------------------------------------------------------------------------
template <int EPI>
__global__ __launch_bounds__(256, 2) void gemm_nt(
    const unsigned short* __restrict__ A, const unsigned short* __restrict__ B,
    float* __restrict__ Cf, unsigned short* __restrict__ Qp,
    unsigned short* __restrict__ Kp, unsigned short* __restrict__ Vp,
    int M, int N, int K) {
  __shared__ __align__(16) unsigned short As[128 * 64];
  __shared__ __align__(16) unsigned short Bs[128 * 64];
  const int tid = threadIdx.x;
  const int m0 = blockIdx.y * 128, n0 = blockIdx.x * 128;
  const int wid = tid >> 6, lane = tid & 63;
  const int wm = wid >> 1, wn = wid & 1;
  const int lr = lane & 15, lg = lane >> 4;

  f32x4 acc[4][4] = {};
  const int T = K >> 6;
  s16x8 pa[4], pb[4];

  #pragma unroll
  for (int j = 0; j < 4; ++j) {
    int c = tid + j * 256, row = c >> 3, cc = c & 7;
    pa[j] = ld8(A + (size_t)(m0 + row) * K + cc * 8);
    pb[j] = ld8(B + (size_t)(n0 + row) * K + cc * 8);
  }

  for (int t = 0; t < T; ++t) {
    __syncthreads();
    #pragma unroll
    for (int j = 0; j < 4; ++j) {
      int c = tid + j * 256, row = c >> 3, cc = c & 7;
      int le = row * 64 + ((cc * 8) ^ ((row & 7) << 3));
      *(s16x8*)&As[le] = pa[j];
      *(s16x8*)&Bs[le] = pb[j];
    }
    __syncthreads();
    if (t + 1 < T) {
      const int k0 = (t + 1) << 6;
      #pragma unroll
      for (int j = 0; j < 4; ++j) {
        int c = tid + j * 256, row = c >> 3, cc = c & 7;
        pa[j] = ld8(A + (size_t)(m0 + row) * K + k0 + cc * 8);
        pb[j] = ld8(B + (size_t)(n0 + row) * K + k0 + cc * 8);
      }
    }
    s16x8 af[4][2], bf[4][2];
    #pragma unroll
    for (int m = 0; m < 4; ++m)
      #pragma unroll
      for (int kk = 0; kk < 2; ++kk) {
        int row = wm * 64 + m * 16 + lr;
        af[m][kk] = *(const s16x8*)&As[row * 64 + ((kk * 32 + lg * 8) ^ ((row & 7) << 3))];
      }
    #pragma unroll
    for (int n = 0; n < 4; ++n)
      #pragma unroll
      for (int kk = 0; kk < 2; ++kk) {
        int row = wn * 64 + n * 16 + lr;
        bf[n][kk] = *(const s16x8*)&Bs[row * 64 + ((kk * 32 + lg * 8) ^ ((row & 7) << 3))];
      }
    #pragma unroll
    for (int kk = 0; kk < 2; ++kk)
      #pragma unroll
      for (int m = 0; m < 4; ++m)
        #pragma unroll
        for (int n = 0; n < 4; ++n)
          acc[m][n] = mfma16x16(af[m][kk], bf[n][kk], acc[m][n]);
  }

  // epilogue  (C/D layout: row = lg*4 + i, col = lr)
  if constexpr (EPI == 0) {
    #pragma unroll
    for (int m = 0; m < 4; ++m)
      #pragma unroll
      for (int i = 0; i < 4; ++i) {
        int r = m0 + wm * 64 + m * 16 + lg * 4 + i;
        #pragma unroll
        for (int n = 0; n < 4; ++n)
          Cf[(size_t)r * N + n0 + wn * 64 + n * 16 + lr] = acc[m][n][i];
      }
  } else {
    const int colb = n0 + wn * 64;          // wave's 64-col span = one head
    const int part = colb >> 10;            // 0=q 1=k 2=v (block-uniform)
    const int h = (colb & 1023) >> 6;
    #pragma unroll
    for (int m = 0; m < 4; ++m)
      #pragma unroll
      for (int i = 0; i < 4; ++i) {
        const int r = m0 + wm * 64 + m * 16 + lg * 4 + i;
        const int b = r >> 11, s = r & 2047;
        const size_t bh = (size_t)b * 16 + h;
        if (part == 2) {
          #pragma unroll
          for (int n = 0; n < 4; ++n)
            Vp[(bh * 64 + n * 16 + lr) * 2048 + s] = f2bf(acc[m][n][i]);
        } else {
          #pragma unroll
          for (int n = 0; n < 2; ++n) {
            const int d = n * 16 + lr;      // 0..31; pair (d, d+32) in-lane
            float ang = (float)s * exp2f((float)d * -0.4152410118609203f);
            float c = __cosf(ang), sn = __sinf(ang);   // HW sin/cos, bf16-accurate
            float x1 = acc[m][n][i], x2 = acc[m][n + 2][i];
            float o1 = x1 * c - x2 * sn;
            float o2 = x2 * c + x1 * sn;
            unsigned short* dst;
            if (part == 0) {
              // fold 1/sqrt(dh) AND log2(e) so attention can use exp2
              o1 *= 0.18033688f; o2 *= 0.18033688f; dst = Qp;
            } else dst = Kp;
            dst[(bh * 2048 + s) * 64 + d] = f2bf(o1);
            dst[(bh * 2048 + s) * 64 + d + 32] = f2bf(o2);
          }
        }
      }
  }
}

// ---------------------------------------------------------------------------
// Causal flash attention — uniform-work version.
// Qr/Kr: bf16 [BH][S][64] (Q pre-scaled by log2e/8), VT: bf16 [BH][64][S],
// Z: bf16 [B*S][1024].
// Block: 4 waves x 16 q-rows = 64 q-rows per q-tile; each block processes the
// q-tile PAIR (p, 31-p) -> exactly 33 KV-tile iterations per block (uniform).
// Grid: 32 bh x 16 pairs = 512 blocks = 2/CU, 8 waves/CU for full duration.
// K and V^T tiles staged in LDS (T2 XOR swizzle); P per-wave in LDS.
// Softmax in base-2 domain (exp2), fully wave-parallel.
// ---------------------------------------------------------------------------
__global__ __launch_bounds__(256, 2) void attn_fwd(
    const unsigned short* __restrict__ Qr, const unsigned short* __restrict__ Kr,
    const unsigned short* __restrict__ VT, unsigned short* __restrict__ Z) {
  __shared__ __align__(16) unsigned short Kl[64 * 64];
  __shared__ __align__(16) unsigned short Vl[64 * 64];
  __shared__ __align__(16) unsigned short Pl[4][16 * 64];
  const int tid = threadIdx.x;
  // XCD-chunked swizzle: 512 blocks % 8 XCDs == 0 -> simple bijective form;
  // each XCD gets 64 consecutive bids = 4 heads (2MB KV working set, L2-fits)
  const int orig = blockIdx.x;
  const int bid = (orig & 7) * 64 + (orig >> 3);
  const int bh = bid >> 4, p = bid & 15;
  const int b = bh >> 4, h = bh & 15;
  const int wid = tid >> 6, lane = tid & 63;
  const int lr = lane & 15, lg = lane >> 4;

  const unsigned short* Qb = Qr + ((size_t)bh << 17);
  const unsigned short* Kb = Kr + ((size_t)bh << 17);
  const unsigned short* Vb = VT + ((size_t)bh << 17);

  #pragma unroll
  for (int side = 0; side < 2; ++side) {
    const int qt = side ? (31 - p) : p;    // q-tile index (64 rows)
    const int qbase = qt << 6;
    const int qw = qbase + wid * 16;       // this wave's first q row
    const int nt = qt + 1;                 // KV tiles 0..qt

    s16x8 qf[2];
    #pragma unroll
    for (int kk = 0; kk < 2; ++kk)
      qf[kk] = ld8(Qb + (size_t)(qw + lr) * 64 + kk * 32 + lg * 8);

    f32x4 oacc[4] = {};
    float mrun[4], lrun[4];
    #pragma unroll
    for (int r = 0; r < 4; ++r) { mrun[r] = -__builtin_inff(); lrun[r] = 0.f; }

    // prologue: prefetch KV tile 0 into registers
    s16x8 pk[2], pv[2];
    #pragma unroll
    for (int j = 0; j < 2; ++j) {
      const int c = tid + j * 256, row = c >> 3, cc = c & 7;
      pk[j] = ld8(Kb + (size_t)row * 64 + cc * 8);
      pv[j] = ld8(Vb + (size_t)row * 2048 + cc * 8);
    }

    for (int t = 0; t < nt; ++t) {
      const int kv0 = t << 6;
      __syncthreads();
      #pragma unroll
      for (int j = 0; j < 2; ++j) {
        const int c = tid + j * 256, row = c >> 3, cc = c & 7;
        const int le = row * 64 + ((cc * 8) ^ ((row & 7) << 3));
        *(s16x8*)&Kl[le] = pk[j];
        *(s16x8*)&Vl[le] = pv[j];
      }
      __syncthreads();
      if (t + 1 < nt) {
        const int kv1 = (t + 1) << 6;
        #pragma unroll
        for (int j = 0; j < 2; ++j) {
          const int c = tid + j * 256, row = c >> 3, cc = c & 7;
          pk[j] = ld8(Kb + (size_t)(kv1 + row) * 64 + cc * 8);
          pv[j] = ld8(Vb + (size_t)row * 2048 + kv1 + cc * 8);
        }
      }

      // S = Q K^T  (scale+log2e already folded into Q)
      f32x4 sacc[4] = {};
      #pragma unroll
      for (int kk = 0; kk < 2; ++kk) {
        s16x8 kf[4];
        #pragma unroll
        for (int n = 0; n < 4; ++n) {
          const int row = n * 16 + lr;
          kf[n] = *(const s16x8*)&Kl[row * 64 + ((kk * 32 + lg * 8) ^ ((row & 7) << 3))];
        }
        #pragma unroll
        for (int n = 0; n < 4; ++n)
          sacc[n] = mfma16x16(qf[kk], kf[n], sacc[n]);
      }

      // online softmax (base-2); lane owns 4 rows (i), 4 cols each (n)
      const bool diag = (t == qt);         // only the diagonal tile masks
      #pragma unroll
      for (int i = 0; i < 4; ++i) {
        const int row = lg * 4 + i;        // local q row 0..15
        const int qabs = qw + row;
        float sv[4];
        float mx = -__builtin_inff();
        #pragma unroll
        for (int n = 0; n < 4; ++n) {
          float v = sacc[n][i];
          if (diag && (kv0 + n * 16 + lr) > qabs) v = -__builtin_inff();
          sv[n] = v;
          mx = fmaxf(mx, v);
        }
        mx = fmaxf(mx, __shfl_xor(mx, 1));
        mx = fmaxf(mx, __shfl_xor(mx, 2));
        mx = fmaxf(mx, __shfl_xor(mx, 4));
        mx = fmaxf(mx, __shfl_xor(mx, 8));
        const float mnew = fmaxf(mrun[i], mx);
        const float alpha = exp2f(mrun[i] - mnew);
        float rs = 0.f;
        #pragma unroll
        for (int n = 0; n < 4; ++n) {
          const float pp = exp2f(sv[n] - mnew);
          rs += pp;
          Pl[wid][row * 64 + ((n * 16 + lr) ^ ((row & 7) << 3))] = (short)f2bf(pp);
        }
        rs += __shfl_xor(rs, 1);
        rs += __shfl_xor(rs, 2);
        rs += __shfl_xor(rs, 4);
        rs += __shfl_xor(rs, 8);
        lrun[i] = lrun[i] * alpha + rs;
        mrun[i] = mnew;
        #pragma unroll
        for (int n = 0; n < 4; ++n) oacc[n][i] *= alpha;
      }

      // own-wave P writes must land before fragment reads (rule 18)
      asm volatile("s_waitcnt lgkmcnt(0)" ::: "memory");
      __builtin_amdgcn_sched_barrier(0);

      // O += P V
      #pragma unroll
      for (int kk = 0; kk < 2; ++kk) {
        s16x8 pf = *(const s16x8*)&Pl[wid][lr * 64 + ((kk * 32 + lg * 8) ^ ((lr & 7) << 3))];
        s16x8 vf[4];
        #pragma unroll
        for (int n = 0; n < 4; ++n) {
          const int row = n * 16 + lr;
          vf[n] = *(const s16x8*)&Vl[row * 64 + ((kk * 32 + lg * 8) ^ ((row & 7) << 3))];
        }
        #pragma unroll
        for (int n = 0; n < 4; ++n)
          oacc[n] = mfma16x16(pf, vf[n], oacc[n]);
      }
    }

    // normalize + write Z[b*S+q][h*64+d] bf16
    #pragma unroll
    for (int i = 0; i < 4; ++i) {
      const float inv = 1.f / lrun[i];
      const int q = qw + lg * 4 + i;
      const size_t base = ((size_t)b * 2048 + q) * 1024 + h * 64;
      #pragma unroll
      for (int n = 0; n < 4; ++n)
        Z[base + n * 16 + lr] = (short)f2bf(oacc[n][i] * inv);
    }
  }
}

// ---------------------------------------------------------------------------
extern "C" void kernel_launch(void* const* d_in, const int* in_sizes, int n_in,
                              void* d_out, int out_size, void* d_ws, size_t ws_size,
                              hipStream_t stream) {
  const float* x     = (const float*)d_in[0];   // [2,2048,1024]
  const float* w_qkv = (const float*)d_in[1];   // [3072,1024]
  const float* w_o   = (const float*)d_in[2];   // [1024,1024]
  float* out = (float*)d_out;                   // [2,2048,1024] fp32

  unsigned short* wsp = (unsigned short*)d_ws;
  unsigned short* Qr  = wsp;                    // [32][2048][64] bf16  (8 MB)
  unsigned short* Kr  = wsp + 4194304;          // [32][2048][64] bf16  (8 MB)
  unsigned short* VT  = wsp + 8388608;          // [32][64][2048] bf16  (8 MB)
  unsigned short* Xb  = wsp + 12582912;         // [4096][1024]  bf16   (8 MB)
  unsigned short* Z   = Xb;                     // aliases Xb (disjoint lifetime)
  unsigned short* Wb  = wsp + 16777216;         // [3072][1024]  bf16   (6 MB)
  unsigned short* Wob = wsp + 19922944;         // [1024][1024]  bf16   (2 MB)
  // total ws use: 40 MiB

  // 0) one-time fp32 -> bf16 conversions (memory-bound)
  cvt_bf16<<<2048, 256, 0, stream>>>(x, Xb, 524288);
  cvt_bf16<<<1536, 256, 0, stream>>>(w_qkv, Wb, 393216);
  cvt_bf16<<<512, 256, 0, stream>>>(w_o, Wob, 131072);

  // 1) QKV projection + fused RoPE/split/transpose epilogue
  gemm_nt<2><<<dim3(24, 32), 256, 0, stream>>>(
      Xb, Wb, nullptr, Qr, Kr, VT, 4096, 3072, 1024);

  // 2) causal flash attention (uniform work: 33 tile-iters per block)
  attn_fwd<<<512, 256, 0, stream>>>(Qr, Kr, VT, Z);

  // 3) output projection (fp32 out)
  gemm_nt<0><<<dim3(8, 32), 256, 0, stream>>>(
      Z, Wob, out, nullptr, nullptr, nullptr, 4096, 1024, 1024);
}

// Round 4
// 132.379 us; speedup vs baseline: 1.7056x; 1.1238x over previous
//
#include <hip/hip_runtime.h>
#include <hip/hip_bf16.h>
#include <cstdint>
#include <cstddef>

#define DEVI static __device__ __forceinline__

typedef short s16x8 __attribute__((ext_vector_type(8)));
typedef float f32x4 __attribute__((ext_vector_type(4)));

DEVI f32x4 mfma16x16(s16x8 a, s16x8 b, f32x4 c) {
  return __builtin_amdgcn_mfma_f32_16x16x32_bf16(a, b, c, 0, 0, 0);
}

// fp32 -> bf16 round-to-nearest-even
DEVI unsigned short f2bf(float f) {
  unsigned u = __builtin_bit_cast(unsigned, f);
  u += 0x7FFFu + ((u >> 16) & 1u);
  return (unsigned short)(u >> 16);
}

DEVI unsigned pk2(float a, float b) {
  return (unsigned)f2bf(a) | ((unsigned)f2bf(b) << 16);
}

DEVI s16x8 ld8(const unsigned short* p) { return *(const s16x8*)p; }

// ---------------------------------------------------------------------------
// fp32 -> bf16 bulk convert (memory-bound)
// ---------------------------------------------------------------------------
__global__ __launch_bounds__(256) void cvt_bf16(
    const float* __restrict__ src, unsigned short* __restrict__ dst, int n8) {
  int i = blockIdx.x * 256 + threadIdx.x;
  if (i >= n8) return;
  const float4* s = (const float4*)src + (size_t)i * 2;
  float4 a = s[0], b = s[1];
  s16x8 r;
  r[0] = (short)f2bf(a.x); r[1] = (short)f2bf(a.y);
  r[2] = (short)f2bf(a.z); r[3] = (short)f2bf(a.w);
  r[4] = (short)f2bf(b.x); r[5] = (short)f2bf(b.y);
  r[6] = (short)f2bf(b.z); r[7] = (short)f2bf(b.w);
  *(s16x8*)(dst + (size_t)i * 8) = r;
}

// ---------------------------------------------------------------------------
// C[m][n] = sum_k A[m][k] * B[n][k]   (NT GEMM, all-bf16 inputs, fp32 acc)
// EPI==0: Cf fp32 [M][N].
// EPI==2: fused qkv split + RoPE epilogue (M=4096, N=3072):
//         cols [0,1024) -> Q (rope, *0.125*log2e) -> Qp[bh][s][64]
//         cols [1024,2048) -> K (rope)            -> Kp[bh][s][64]
//         cols [2048,3072) -> V                   -> Vp[bh][64][2048] (transposed)
// 128x128x64 tiles, 256 threads (2x2 waves of 64x64), reg-staged LDS with
// T2 XOR swizzle (elem ^= (row&7)<<3) -> conflict-free ds_read_b128.
// ---------------------------------------------------------------------------
template <int EPI>
__global__ __launch_bounds__(256, 2) void gemm_nt(
    const unsigned short* __restrict__ A, const unsigned short* __restrict__ B,
    float* __restrict__ Cf, unsigned short* __restrict__ Qp,
    unsigned short* __restrict__ Kp, unsigned short* __restrict__ Vp,
    int M, int N, int K) {
  __shared__ __align__(16) unsigned short As[128 * 64];
  __shared__ __align__(16) unsigned short Bs[128 * 64];
  const int tid = threadIdx.x;
  const int m0 = blockIdx.y * 128, n0 = blockIdx.x * 128;
  const int wid = tid >> 6, lane = tid & 63;
  const int wm = wid >> 1, wn = wid & 1;
  const int lr = lane & 15, lg = lane >> 4;

  f32x4 acc[4][4] = {};
  const int T = K >> 6;
  s16x8 pa[4], pb[4];

  #pragma unroll
  for (int j = 0; j < 4; ++j) {
    int c = tid + j * 256, row = c >> 3, cc = c & 7;
    pa[j] = ld8(A + (size_t)(m0 + row) * K + cc * 8);
    pb[j] = ld8(B + (size_t)(n0 + row) * K + cc * 8);
  }

  for (int t = 0; t < T; ++t) {
    __syncthreads();
    #pragma unroll
    for (int j = 0; j < 4; ++j) {
      int c = tid + j * 256, row = c >> 3, cc = c & 7;
      int le = row * 64 + ((cc * 8) ^ ((row & 7) << 3));
      *(s16x8*)&As[le] = pa[j];
      *(s16x8*)&Bs[le] = pb[j];
    }
    __syncthreads();
    if (t + 1 < T) {
      const int k0 = (t + 1) << 6;
      #pragma unroll
      for (int j = 0; j < 4; ++j) {
        int c = tid + j * 256, row = c >> 3, cc = c & 7;
        pa[j] = ld8(A + (size_t)(m0 + row) * K + k0 + cc * 8);
        pb[j] = ld8(B + (size_t)(n0 + row) * K + k0 + cc * 8);
      }
    }
    s16x8 af[4][2], bf[4][2];
    #pragma unroll
    for (int m = 0; m < 4; ++m)
      #pragma unroll
      for (int kk = 0; kk < 2; ++kk) {
        int row = wm * 64 + m * 16 + lr;
        af[m][kk] = *(const s16x8*)&As[row * 64 + ((kk * 32 + lg * 8) ^ ((row & 7) << 3))];
      }
    #pragma unroll
    for (int n = 0; n < 4; ++n)
      #pragma unroll
      for (int kk = 0; kk < 2; ++kk) {
        int row = wn * 64 + n * 16 + lr;
        bf[n][kk] = *(const s16x8*)&Bs[row * 64 + ((kk * 32 + lg * 8) ^ ((row & 7) << 3))];
      }
    #pragma unroll
    for (int kk = 0; kk < 2; ++kk)
      #pragma unroll
      for (int m = 0; m < 4; ++m)
        #pragma unroll
        for (int n = 0; n < 4; ++n)
          acc[m][n] = mfma16x16(af[m][kk], bf[n][kk], acc[m][n]);
  }

  // epilogue  (C/D layout: row = lg*4 + i, col = lr)
  if constexpr (EPI == 0) {
    #pragma unroll
    for (int m = 0; m < 4; ++m)
      #pragma unroll
      for (int i = 0; i < 4; ++i) {
        int r = m0 + wm * 64 + m * 16 + lg * 4 + i;
        #pragma unroll
        for (int n = 0; n < 4; ++n)
          Cf[(size_t)r * N + n0 + wn * 64 + n * 16 + lr] = acc[m][n][i];
      }
  } else {
    const int colb = n0 + wn * 64;          // wave's 64-col span = one head
    const int part = colb >> 10;            // 0=q 1=k 2=v (block-uniform)
    const int h = (colb & 1023) >> 6;
    #pragma unroll
    for (int m = 0; m < 4; ++m)
      #pragma unroll
      for (int i = 0; i < 4; ++i) {
        const int r = m0 + wm * 64 + m * 16 + lg * 4 + i;
        const int b = r >> 11, s = r & 2047;
        const size_t bh = (size_t)b * 16 + h;
        if (part == 2) {
          #pragma unroll
          for (int n = 0; n < 4; ++n)
            Vp[(bh * 64 + n * 16 + lr) * 2048 + s] = f2bf(acc[m][n][i]);
        } else {
          #pragma unroll
          for (int n = 0; n < 2; ++n) {
            const int d = n * 16 + lr;      // 0..31; pair (d, d+32) in-lane
            float ang = (float)s * exp2f((float)d * -0.4152410118609203f);
            float c = __cosf(ang), sn = __sinf(ang);   // HW sin/cos, bf16-accurate
            float x1 = acc[m][n][i], x2 = acc[m][n + 2][i];
            float o1 = x1 * c - x2 * sn;
            float o2 = x2 * c + x1 * sn;
            unsigned short* dst;
            if (part == 0) {
              // fold 1/sqrt(dh) AND log2(e) so attention can use exp2
              o1 *= 0.18033688f; o2 *= 0.18033688f; dst = Qp;
            } else dst = Kp;
            dst[(bh * 2048 + s) * 64 + d] = f2bf(o1);
            dst[(bh * 2048 + s) * 64 + d + 32] = f2bf(o2);
          }
        }
      }
  }
}

// ---------------------------------------------------------------------------
// Causal flash attention — swapped-operand softmax version.
// Qr/Kr: bf16 [BH][S][64] (Q pre-scaled by log2e/8), VT: bf16 [BH][64][S],
// Z: bf16 [B*S][1024].
// Block: 2 waves x 16 q-rows = 32-row q-tile; block processes the q-tile
// PAIR (p, 63-p) -> exactly 33 KV-tile (64-wide) iterations per block.
// Grid: 32 bh x 32 pairs = 1024 blocks = 4 independent streams/CU.
// QK^T computed SWAPPED: mfma(K, Q) -> C[k][q] with q = lane&15 lane-local.
// Each lane owns ONE q-row: row max/sum = in-lane tree + 2 shfl (xor 16,32).
// PV computed as mfma(V^T, P) -> O^T[d][q]: alpha/inv rescale lane-uniform.
// ---------------------------------------------------------------------------
__global__ __launch_bounds__(128, 2) void attn_fwd(
    const unsigned short* __restrict__ Qr, const unsigned short* __restrict__ Kr,
    const unsigned short* __restrict__ VT, unsigned short* __restrict__ Z) {
  __shared__ __align__(16) unsigned short Kl[64 * 64];
  __shared__ __align__(16) unsigned short Vl[64 * 64];
  __shared__ __align__(16) unsigned short Pl[2][16 * 64];
  const int tid = threadIdx.x;
  // XCD-chunked swizzle (1024 % 8 == 0 -> bijective): 128 bids/XCD = 4 heads,
  // ~2MB KV working set per XCD L2.
  const int orig = blockIdx.x;
  const int bid = (orig & 7) * 128 + (orig >> 3);
  const int bh = bid >> 5, p = bid & 31;
  const int b = bh >> 4, h = bh & 15;
  const int wid = tid >> 6, lane = tid & 63;
  const int lr = lane & 15, lg = lane >> 4;

  const unsigned short* Qb = Qr + ((size_t)bh << 17);
  const unsigned short* Kb = Kr + ((size_t)bh << 17);
  const unsigned short* Vb = VT + ((size_t)bh << 17);

  #pragma unroll
  for (int side = 0; side < 2; ++side) {
    const int qt = side ? (63 - p) : p;    // 32-row q-tile index
    const int qw = qt * 32 + wid * 16;     // wave's first q row
    const int qabs = qw + lr;              // THE q-row this lane owns
    const int nt = (qt >> 1) + 1;          // KV tiles 0..nt-1

    s16x8 qf[2];
    #pragma unroll
    for (int kk = 0; kk < 2; ++kk)
      qf[kk] = ld8(Qb + (size_t)(qw + lr) * 64 + kk * 32 + lg * 8);

    f32x4 oacc[4] = {};                    // O^T[d = n*16+lg*4+i][q = lr]
    float mrun = -__builtin_inff(), lrun = 0.f;

    // prologue: prefetch KV tile 0 into registers (128 threads, 4 chunks each)
    s16x8 pk[4], pv[4];
    #pragma unroll
    for (int j = 0; j < 4; ++j) {
      const int c = tid + j * 128, row = c >> 3, cc = c & 7;
      pk[j] = ld8(Kb + (size_t)row * 64 + cc * 8);
      pv[j] = ld8(Vb + (size_t)row * 2048 + cc * 8);
    }

    for (int t = 0; t < nt; ++t) {
      const int kv0 = t << 6;
      __syncthreads();
      #pragma unroll
      for (int j = 0; j < 4; ++j) {
        const int c = tid + j * 128, row = c >> 3, cc = c & 7;
        const int le = row * 64 + ((cc * 8) ^ ((row & 7) << 3));
        *(s16x8*)&Kl[le] = pk[j];
        *(s16x8*)&Vl[le] = pv[j];
      }
      __syncthreads();
      if (t + 1 < nt) {
        const int kv1 = (t + 1) << 6;
        #pragma unroll
        for (int j = 0; j < 4; ++j) {
          const int c = tid + j * 128, row = c >> 3, cc = c & 7;
          pk[j] = ld8(Kb + (size_t)(kv1 + row) * 64 + cc * 8);
          pv[j] = ld8(Vb + (size_t)row * 2048 + kv1 + cc * 8);
        }
      }

      // S^T = K Q^T (swapped): sacc[n][i] = S[k = kv0+n*16+lg*4+i][q = qabs]
      f32x4 sacc[4] = {};
      __builtin_amdgcn_s_setprio(1);
      #pragma unroll
      for (int kk = 0; kk < 2; ++kk) {
        s16x8 kf[4];
        #pragma unroll
        for (int n = 0; n < 4; ++n) {
          const int row = n * 16 + lr;
          kf[n] = *(const s16x8*)&Kl[row * 64 + ((kk * 32 + lg * 8) ^ ((row & 7) << 3))];
        }
        #pragma unroll
        for (int n = 0; n < 4; ++n)
          sacc[n] = mfma16x16(kf[n], qf[kk], sacc[n]);   // A=K rows, B=Q rows
      }
      __builtin_amdgcn_s_setprio(0);

      // causal mask (only the diagonal tile)
      if (t == nt - 1) {
        #pragma unroll
        for (int n = 0; n < 4; ++n)
          #pragma unroll
          for (int i = 0; i < 4; ++i)
            if (kv0 + n * 16 + lg * 4 + i > qabs) sacc[n][i] = -__builtin_inff();
      }

      // in-lane max tree (16 values) + 2 shfl across the 4 lanes sharing q
      float mn[4];
      #pragma unroll
      for (int n = 0; n < 4; ++n)
        mn[n] = fmaxf(fmaxf(sacc[n][0], sacc[n][1]), fmaxf(sacc[n][2], sacc[n][3]));
      float mx = fmaxf(fmaxf(mn[0], mn[1]), fmaxf(mn[2], mn[3]));
      mx = fmaxf(mx, __shfl_xor(mx, 16));
      mx = fmaxf(mx, __shfl_xor(mx, 32));
      const float mnew = fmaxf(mrun, mx);
      const float alpha = exp2f(mrun - mnew);
      mrun = mnew;

      // exp2 (base-2 domain; log2e folded into Q), sum tree, pack P -> LDS
      float pr[4][4];
      float sn[4];
      #pragma unroll
      for (int n = 0; n < 4; ++n) {
        #pragma unroll
        for (int i = 0; i < 4; ++i) pr[n][i] = exp2f(sacc[n][i] - mnew);
        sn[n] = (pr[n][0] + pr[n][1]) + (pr[n][2] + pr[n][3]);
        uint2 u;
        u.x = pk2(pr[n][0], pr[n][1]);
        u.y = pk2(pr[n][2], pr[n][3]);
        // P stored [q=lr][k] row-major with XOR swizzle; phys(k) = k ^ ((lr&7)<<3)
        *(uint2*)&Pl[wid][lr * 64 + ((n * 16 + lg * 4) ^ ((lr & 7) << 3))] = u;
      }
      float rs = (sn[0] + sn[1]) + (sn[2] + sn[3]);
      rs += __shfl_xor(rs, 16);
      rs += __shfl_xor(rs, 32);
      lrun = lrun * alpha + rs;
      #pragma unroll
      for (int n = 0; n < 4; ++n)
        #pragma unroll
        for (int i = 0; i < 4; ++i) oacc[n][i] *= alpha;   // alpha lane-uniform

      // own-wave P writes must land before fragment reads (rule 18)
      asm volatile("s_waitcnt lgkmcnt(0)" ::: "memory");
      __builtin_amdgcn_sched_barrier(0);

      // O^T += V^T P^T : mfma(A=V^T rows d, B=P rows q) -> C[d][q]
      __builtin_amdgcn_s_setprio(1);
      #pragma unroll
      for (int kk = 0; kk < 2; ++kk) {
        s16x8 pf = *(const s16x8*)&Pl[wid][lr * 64 + ((kk * 32 + lg * 8) ^ ((lr & 7) << 3))];
        s16x8 vf[4];
        #pragma unroll
        for (int n = 0; n < 4; ++n) {
          const int row = n * 16 + lr;
          vf[n] = *(const s16x8*)&Vl[row * 64 + ((kk * 32 + lg * 8) ^ ((row & 7) << 3))];
        }
        #pragma unroll
        for (int n = 0; n < 4; ++n)
          oacc[n] = mfma16x16(vf[n], pf, oacc[n]);
      }
      __builtin_amdgcn_s_setprio(0);
    }

    // normalize (lane-uniform) + write Z[b*S+q][h*64+d], 4x dwordx2 per lane
    const float inv = 1.f / lrun;
    const size_t base = ((size_t)b * 2048 + qabs) * 1024 + h * 64;
    #pragma unroll
    for (int n = 0; n < 4; ++n) {
      uint2 u;
      u.x = pk2(oacc[n][0] * inv, oacc[n][1] * inv);
      u.y = pk2(oacc[n][2] * inv, oacc[n][3] * inv);
      *(uint2*)&Z[base + n * 16 + lg * 4] = u;
    }
  }
}

// ---------------------------------------------------------------------------
extern "C" void kernel_launch(void* const* d_in, const int* in_sizes, int n_in,
                              void* d_out, int out_size, void* d_ws, size_t ws_size,
                              hipStream_t stream) {
  const float* x     = (const float*)d_in[0];   // [2,2048,1024]
  const float* w_qkv = (const float*)d_in[1];   // [3072,1024]
  const float* w_o   = (const float*)d_in[2];   // [1024,1024]
  float* out = (float*)d_out;                   // [2,2048,1024] fp32

  unsigned short* wsp = (unsigned short*)d_ws;
  unsigned short* Qr  = wsp;                    // [32][2048][64] bf16  (8 MB)
  unsigned short* Kr  = wsp + 4194304;          // [32][2048][64] bf16  (8 MB)
  unsigned short* VT  = wsp + 8388608;          // [32][64][2048] bf16  (8 MB)
  unsigned short* Xb  = wsp + 12582912;         // [4096][1024]  bf16   (8 MB)
  unsigned short* Z   = Xb;                     // aliases Xb (disjoint lifetime)
  unsigned short* Wb  = wsp + 16777216;         // [3072][1024]  bf16   (6 MB)
  unsigned short* Wob = wsp + 19922944;         // [1024][1024]  bf16   (2 MB)
  // total ws use: 40 MiB

  // 0) one-time fp32 -> bf16 conversions (memory-bound)
  cvt_bf16<<<2048, 256, 0, stream>>>(x, Xb, 524288);
  cvt_bf16<<<1536, 256, 0, stream>>>(w_qkv, Wb, 393216);
  cvt_bf16<<<512, 256, 0, stream>>>(w_o, Wob, 131072);

  // 1) QKV projection + fused RoPE/split/transpose epilogue
  gemm_nt<2><<<dim3(24, 32), 256, 0, stream>>>(
      Xb, Wb, nullptr, Qr, Kr, VT, 4096, 3072, 1024);

  // 2) causal flash attention (swapped softmax, 33 tile-iters per block)
  attn_fwd<<<1024, 128, 0, stream>>>(Qr, Kr, VT, Z);

  // 3) output projection (fp32 out)
  gemm_nt<0><<<dim3(8, 32), 256, 0, stream>>>(
      Z, Wob, out, nullptr, nullptr, nullptr, 4096, 1024, 1024);
}

// Round 5
// 126.664 us; speedup vs baseline: 1.7825x; 1.0451x over previous
//
#include <hip/hip_runtime.h>
#include <hip/hip_bf16.h>
#include <cstdint>
#include <cstddef>

#define DEVI static __device__ __forceinline__

typedef short s16x8 __attribute__((ext_vector_type(8)));
typedef float f32x4 __attribute__((ext_vector_type(4)));

DEVI f32x4 mfma16x16(s16x8 a, s16x8 b, f32x4 c) {
  return __builtin_amdgcn_mfma_f32_16x16x32_bf16(a, b, c, 0, 0, 0);
}

// HW float->bf16 (compiler emits v_cvt / cvt_pk on gfx950 — m240)
DEVI unsigned short hcvt(float f) {
  return __builtin_bit_cast(unsigned short, __float2bfloat16(f));
}
DEVI unsigned pk2(float a, float b) {
  return (unsigned)hcvt(a) | ((unsigned)hcvt(b) << 16);
}

DEVI s16x8 ld8(const unsigned short* p) { return *(const s16x8*)p; }

// async global->LDS, 16B per lane; dest = wave-uniform base + lane*16
DEVI void gload16(const void* g, void* l) {
  __builtin_amdgcn_global_load_lds(
      (const __attribute__((address_space(1))) void*)g,
      (__attribute__((address_space(3))) void*)l, 16, 0, 0);
}

// ---------------------------------------------------------------------------
// fused fp32 -> bf16 bulk convert of all three inputs (one launch)
// ranges (in 8-elem units): x 524288 | w_qkv 393216 | w_o 131072
// ---------------------------------------------------------------------------
__global__ __launch_bounds__(256) void cvt_all(
    const float* __restrict__ x, const float* __restrict__ w1,
    const float* __restrict__ w2, unsigned short* __restrict__ Xb,
    unsigned short* __restrict__ Wb, unsigned short* __restrict__ Wob) {
  int i = blockIdx.x * 256 + threadIdx.x;   // [0, 1048576)
  const float* s;
  unsigned short* d;
  int off;
  if (i < 524288) { s = x; d = Xb; off = i; }
  else if (i < 917504) { s = w1; d = Wb; off = i - 524288; }
  else { s = w2; d = Wob; off = i - 917504; }
  const float4* sp = (const float4*)s + (size_t)off * 2;
  float4 a = sp[0], b = sp[1];
  s16x8 r;
  r[0] = (short)hcvt(a.x); r[1] = (short)hcvt(a.y);
  r[2] = (short)hcvt(a.z); r[3] = (short)hcvt(a.w);
  r[4] = (short)hcvt(b.x); r[5] = (short)hcvt(b.y);
  r[6] = (short)hcvt(b.z); r[7] = (short)hcvt(b.w);
  *(s16x8*)(d + (size_t)off * 8) = r;
}

// ---------------------------------------------------------------------------
// C[m][n] = sum_k A[m][k] * B[n][k]   (NT GEMM, bf16 in, fp32 acc)
// STAGE==1: global_load_lds staging (m97 2-barrier loop), swizzle applied by
//           permuting the per-lane GLOBAL chunk (rule 21): ck = (c&7)^(row&7).
// STAGE==0: reg-staged with in-wave prefetch (for low-occupancy grids).
// EPI==0: Cf fp32 [M][N].
// EPI==2: fused qkv split + RoPE epilogue (see round-2 notes).
// ---------------------------------------------------------------------------
template <int EPI, int STAGE>
__global__ __launch_bounds__(256, 2) void gemm_nt(
    const unsigned short* __restrict__ A, const unsigned short* __restrict__ B,
    float* __restrict__ Cf, unsigned short* __restrict__ Qp,
    unsigned short* __restrict__ Kp, unsigned short* __restrict__ Vp,
    int M, int N, int K) {
  __shared__ __align__(16) unsigned short As[128 * 64];
  __shared__ __align__(16) unsigned short Bs[128 * 64];
  const int tid = threadIdx.x;
  const int m0 = blockIdx.y * 128, n0 = blockIdx.x * 128;
  const int wid = tid >> 6, lane = tid & 63;
  const int wm = wid >> 1, wn = wid & 1;
  const int lr = lane & 15, lg = lane >> 4;

  f32x4 acc[4][4] = {};
  const int T = K >> 6;

  auto compute_step = [&]() {
    s16x8 af[4][2], bf[4][2];
    #pragma unroll
    for (int m = 0; m < 4; ++m)
      #pragma unroll
      for (int kk = 0; kk < 2; ++kk) {
        int row = wm * 64 + m * 16 + lr;
        af[m][kk] = *(const s16x8*)&As[row * 64 + ((kk * 32 + lg * 8) ^ ((row & 7) << 3))];
      }
    #pragma unroll
    for (int n = 0; n < 4; ++n)
      #pragma unroll
      for (int kk = 0; kk < 2; ++kk) {
        int row = wn * 64 + n * 16 + lr;
        bf[n][kk] = *(const s16x8*)&Bs[row * 64 + ((kk * 32 + lg * 8) ^ ((row & 7) << 3))];
      }
    #pragma unroll
    for (int kk = 0; kk < 2; ++kk)
      #pragma unroll
      for (int m = 0; m < 4; ++m)
        #pragma unroll
        for (int n = 0; n < 4; ++n)
          acc[m][n] = mfma16x16(af[m][kk], bf[n][kk], acc[m][n]);
  };

  if constexpr (STAGE == 1) {
    for (int t = 0; t < T; ++t) {
      const int k0 = t << 6;
      __syncthreads();                      // all waves done reading prev tile
      #pragma unroll
      for (int j = 0; j < 4; ++j) {
        const int c = j * 256 + tid;
        const int row = c >> 3;
        const int ck = (c & 7) ^ (row & 7); // pre-swizzled source chunk
        gload16(A + (size_t)(m0 + row) * K + k0 + ck * 8,
                &As[(j * 256 + (tid & 192)) * 8]);
        gload16(B + (size_t)(n0 + row) * K + k0 + ck * 8,
                &Bs[(j * 256 + (tid & 192)) * 8]);
      }
      asm volatile("s_waitcnt vmcnt(0)" ::: "memory");
      __syncthreads();
      compute_step();
    }
  } else {
    s16x8 pa[4], pb[4];
    #pragma unroll
    for (int j = 0; j < 4; ++j) {
      int c = tid + j * 256, row = c >> 3, cc = c & 7;
      pa[j] = ld8(A + (size_t)(m0 + row) * K + cc * 8);
      pb[j] = ld8(B + (size_t)(n0 + row) * K + cc * 8);
    }
    for (int t = 0; t < T; ++t) {
      __syncthreads();
      #pragma unroll
      for (int j = 0; j < 4; ++j) {
        int c = tid + j * 256, row = c >> 3, cc = c & 7;
        int le = row * 64 + ((cc * 8) ^ ((row & 7) << 3));
        *(s16x8*)&As[le] = pa[j];
        *(s16x8*)&Bs[le] = pb[j];
      }
      __syncthreads();
      if (t + 1 < T) {
        const int k0 = (t + 1) << 6;
        #pragma unroll
        for (int j = 0; j < 4; ++j) {
          int c = tid + j * 256, row = c >> 3, cc = c & 7;
          pa[j] = ld8(A + (size_t)(m0 + row) * K + k0 + cc * 8);
          pb[j] = ld8(B + (size_t)(n0 + row) * K + k0 + cc * 8);
        }
      }
      compute_step();
    }
  }

  // epilogue  (C/D layout: row = lg*4 + i, col = lr)
  if constexpr (EPI == 0) {
    #pragma unroll
    for (int m = 0; m < 4; ++m)
      #pragma unroll
      for (int i = 0; i < 4; ++i) {
        int r = m0 + wm * 64 + m * 16 + lg * 4 + i;
        #pragma unroll
        for (int n = 0; n < 4; ++n)
          Cf[(size_t)r * N + n0 + wn * 64 + n * 16 + lr] = acc[m][n][i];
      }
  } else {
    const int colb = n0 + wn * 64;          // wave's 64-col span = one head
    const int part = colb >> 10;            // 0=q 1=k 2=v (block-uniform)
    const int h = (colb & 1023) >> 6;
    #pragma unroll
    for (int m = 0; m < 4; ++m)
      #pragma unroll
      for (int i = 0; i < 4; ++i) {
        const int r = m0 + wm * 64 + m * 16 + lg * 4 + i;
        const int b = r >> 11, s = r & 2047;
        const size_t bh = (size_t)b * 16 + h;
        if (part == 2) {
          #pragma unroll
          for (int n = 0; n < 4; ++n)
            Vp[(bh * 64 + n * 16 + lr) * 2048 + s] = hcvt(acc[m][n][i]);
        } else {
          #pragma unroll
          for (int n = 0; n < 2; ++n) {
            const int d = n * 16 + lr;      // 0..31; pair (d, d+32) in-lane
            float ang = (float)s * exp2f((float)d * -0.4152410118609203f);
            float c = __cosf(ang), sn = __sinf(ang);
            float x1 = acc[m][n][i], x2 = acc[m][n + 2][i];
            float o1 = x1 * c - x2 * sn;
            float o2 = x2 * c + x1 * sn;
            unsigned short* dst;
            if (part == 0) {
              // fold 1/sqrt(dh) AND log2(e) so attention can use exp2
              o1 *= 0.18033688f; o2 *= 0.18033688f; dst = Qp;
            } else dst = Kp;
            dst[(bh * 2048 + s) * 64 + d] = hcvt(o1);
            dst[(bh * 2048 + s) * 64 + d + 32] = hcvt(o2);
          }
        }
      }
  }
}

// ---------------------------------------------------------------------------
// Causal flash attention — swapped softmax + dbuf global_load_lds + defer-max.
// Qr/Kr: bf16 [BH][S][64] (Q pre-scaled by log2e/8), VT: bf16 [BH][64][S],
// Z: bf16 [B*S][1024].
// Block: 2 waves x 16 q-rows; q-tile pair (p, 63-p) -> 33 iters/block.
// Grid: 1024 blocks (XCD-chunked) = 4/CU. K/V double-buffered in LDS via
// global_load_lds with pre-swizzled source; next tile staged during compute
// (T3 minimum 2-phase). Defer-max (T13, THR=8 in log2 units).
// ---------------------------------------------------------------------------
__global__ __launch_bounds__(128, 2) void attn_fwd(
    const unsigned short* __restrict__ Qr, const unsigned short* __restrict__ Kr,
    const unsigned short* __restrict__ VT, unsigned short* __restrict__ Z) {
  __shared__ __align__(16) unsigned short Kl[2][64 * 64];
  __shared__ __align__(16) unsigned short Vl[2][64 * 64];
  __shared__ __align__(16) unsigned short Pl[2][16 * 64];
  const int tid = threadIdx.x;
  const int orig = blockIdx.x;
  const int bid = (orig & 7) * 128 + (orig >> 3);   // XCD-chunked, bijective
  const int bh = bid >> 5, p = bid & 31;
  const int b = bh >> 4, h = bh & 15;
  const int wid = tid >> 6, lane = tid & 63;
  const int lr = lane & 15, lg = lane >> 4;

  const unsigned short* Qb = Qr + ((size_t)bh << 17);
  const unsigned short* Kb = Kr + ((size_t)bh << 17);
  const unsigned short* Vb = VT + ((size_t)bh << 17);

  // per-lane staging geometry (loop-invariant)
  const int s_row0 = tid >> 3;              // rows tid/8 + j*16
  const int s_ck0 = tid & 7;

  #pragma unroll
  for (int side = 0; side < 2; ++side) {
    const int qt = side ? (63 - p) : p;     // 32-row q-tile index
    const int qw = qt * 32 + wid * 16;      // wave's first q row
    const int qabs = qw + lr;               // THE q-row this lane owns
    const int nt = (qt >> 1) + 1;           // KV tiles 0..nt-1

    s16x8 qf[2];
    #pragma unroll
    for (int kk = 0; kk < 2; ++kk)
      qf[kk] = ld8(Qb + (size_t)(qw + lr) * 64 + kk * 32 + lg * 8);

    f32x4 oacc[4] = {};                     // O^T[d = n*16+lg*4+i][q = lr]
    float mrun = -__builtin_inff(), lrun = 0.f;

    auto STAGE = [&](int buf, int t2) {
      const int kv = t2 << 6;
      #pragma unroll
      for (int j = 0; j < 4; ++j) {
        const int row = s_row0 + j * 16;
        const int ck = s_ck0 ^ (row & 7);   // pre-swizzled source chunk
        gload16(Kb + (size_t)(kv + row) * 64 + ck * 8,
                &Kl[buf][(j * 128 + (tid & 64)) * 8]);
        gload16(Vb + (size_t)row * 2048 + kv + ck * 8,
                &Vl[buf][(j * 128 + (tid & 64)) * 8]);
      }
    };

    // prologue: stage tile 0
    STAGE(0, 0);
    asm volatile("s_waitcnt vmcnt(0)" ::: "memory");
    __syncthreads();
    int cur = 0;

    for (int t = 0; t < nt; ++t) {
      const int kv0 = t << 6;
      if (t + 1 < nt) STAGE(cur ^ 1, t + 1);   // overlap with compute below

      // S^T = K Q^T (swapped): sacc[n][i] = S[k = kv0+n*16+lg*4+i][q = qabs]
      f32x4 sacc[4] = {};
      __builtin_amdgcn_s_setprio(1);
      #pragma unroll
      for (int kk = 0; kk < 2; ++kk) {
        s16x8 kf[4];
        #pragma unroll
        for (int n = 0; n < 4; ++n) {
          const int row = n * 16 + lr;
          kf[n] = *(const s16x8*)&Kl[cur][row * 64 + ((kk * 32 + lg * 8) ^ ((row & 7) << 3))];
        }
        #pragma unroll
        for (int n = 0; n < 4; ++n)
          sacc[n] = mfma16x16(kf[n], qf[kk], sacc[n]);
      }
      __builtin_amdgcn_s_setprio(0);

      // causal mask (diagonal tile only)
      if (t == nt - 1) {
        #pragma unroll
        for (int n = 0; n < 4; ++n)
          #pragma unroll
          for (int i = 0; i < 4; ++i)
            if (kv0 + n * 16 + lg * 4 + i > qabs) sacc[n][i] = -__builtin_inff();
      }

      // row max: in-lane tree + 2 shfl across the 4 lanes sharing q
      float mn[4];
      #pragma unroll
      for (int n = 0; n < 4; ++n)
        mn[n] = fmaxf(fmaxf(sacc[n][0], sacc[n][1]), fmaxf(sacc[n][2], sacc[n][3]));
      float mx = fmaxf(fmaxf(mn[0], mn[1]), fmaxf(mn[2], mn[3]));
      mx = fmaxf(mx, __shfl_xor(mx, 16));
      mx = fmaxf(mx, __shfl_xor(mx, 32));

      // defer-max (T13): only rescale when max grew by > 8 (log2 domain)
      if (__any(mx > mrun + 8.f)) {
        const float mnew = fmaxf(mrun, mx);
        const float alpha = exp2f(mrun - mnew);
        lrun *= alpha;
        #pragma unroll
        for (int n = 0; n < 4; ++n)
          #pragma unroll
          for (int i = 0; i < 4; ++i) oacc[n][i] *= alpha;
        mrun = mnew;
      }

      // P = exp2(S - mrun)  (bounded by 2^8), pack via HW cvt -> LDS
      float rs = 0.f;
      #pragma unroll
      for (int n = 0; n < 4; ++n) {
        float p0 = exp2f(sacc[n][0] - mrun), p1 = exp2f(sacc[n][1] - mrun);
        float p2 = exp2f(sacc[n][2] - mrun), p3 = exp2f(sacc[n][3] - mrun);
        rs += (p0 + p1) + (p2 + p3);
        uint2 u;
        u.x = pk2(p0, p1);
        u.y = pk2(p2, p3);
        *(uint2*)&Pl[wid][lr * 64 + ((n * 16 + lg * 4) ^ ((lr & 7) << 3))] = u;
      }
      rs += __shfl_xor(rs, 16);
      rs += __shfl_xor(rs, 32);
      lrun += rs;

      // own-wave P writes must land before fragment reads (rule 18)
      asm volatile("s_waitcnt lgkmcnt(0)" ::: "memory");
      __builtin_amdgcn_sched_barrier(0);

      // O^T += V^T P^T : mfma(A=V^T rows d, B=P rows q) -> C[d][q]
      __builtin_amdgcn_s_setprio(1);
      #pragma unroll
      for (int kk = 0; kk < 2; ++kk) {
        s16x8 pf = *(const s16x8*)&Pl[wid][lr * 64 + ((kk * 32 + lg * 8) ^ ((lr & 7) << 3))];
        s16x8 vf[4];
        #pragma unroll
        for (int n = 0; n < 4; ++n) {
          const int row = n * 16 + lr;
          vf[n] = *(const s16x8*)&Vl[cur][row * 64 + ((kk * 32 + lg * 8) ^ ((row & 7) << 3))];
        }
        #pragma unroll
        for (int n = 0; n < 4; ++n)
          oacc[n] = mfma16x16(vf[n], pf, oacc[n]);
      }
      __builtin_amdgcn_s_setprio(0);

      // next tile's loads done + everyone finished reading buf cur
      asm volatile("s_waitcnt vmcnt(0)" ::: "memory");
      __syncthreads();
      cur ^= 1;
    }

    // normalize (lane-uniform) + write Z[b*S+q][h*64+d], 4x dwordx2 per lane
    const float inv = 1.f / lrun;
    const size_t base = ((size_t)b * 2048 + qabs) * 1024 + h * 64;
    #pragma unroll
    for (int n = 0; n < 4; ++n) {
      uint2 u;
      u.x = pk2(oacc[n][0] * inv, oacc[n][1] * inv);
      u.y = pk2(oacc[n][2] * inv, oacc[n][3] * inv);
      *(uint2*)&Z[base + n * 16 + lg * 4] = u;
    }
  }
}

// ---------------------------------------------------------------------------
extern "C" void kernel_launch(void* const* d_in, const int* in_sizes, int n_in,
                              void* d_out, int out_size, void* d_ws, size_t ws_size,
                              hipStream_t stream) {
  const float* x     = (const float*)d_in[0];   // [2,2048,1024]
  const float* w_qkv = (const float*)d_in[1];   // [3072,1024]
  const float* w_o   = (const float*)d_in[2];   // [1024,1024]
  float* out = (float*)d_out;                   // [2,2048,1024] fp32

  unsigned short* wsp = (unsigned short*)d_ws;
  unsigned short* Qr  = wsp;                    // [32][2048][64] bf16  (8 MB)
  unsigned short* Kr  = wsp + 4194304;          // [32][2048][64] bf16  (8 MB)
  unsigned short* VT  = wsp + 8388608;          // [32][64][2048] bf16  (8 MB)
  unsigned short* Xb  = wsp + 12582912;         // [4096][1024]  bf16   (8 MB)
  unsigned short* Z   = Xb;                     // aliases Xb (disjoint lifetime)
  unsigned short* Wb  = wsp + 16777216;         // [3072][1024]  bf16   (6 MB)
  unsigned short* Wob = wsp + 19922944;         // [1024][1024]  bf16   (2 MB)
  // total ws use: 40 MiB

  // 0) fused one-time fp32 -> bf16 conversions
  cvt_all<<<4096, 256, 0, stream>>>(x, w_qkv, w_o, Xb, Wb, Wob);

  // 1) QKV projection (global_load_lds staging) + fused RoPE epilogue
  gemm_nt<2, 1><<<dim3(24, 32), 256, 0, stream>>>(
      Xb, Wb, nullptr, Qr, Kr, VT, 4096, 3072, 1024);

  // 2) causal flash attention
  attn_fwd<<<1024, 128, 0, stream>>>(Qr, Kr, VT, Z);

  // 3) output projection (reg-staged; 1 block/CU grid) (fp32 out)
  gemm_nt<0, 0><<<dim3(8, 32), 256, 0, stream>>>(
      Z, Wob, out, nullptr, nullptr, nullptr, 4096, 1024, 1024);
}

// Round 6
// 123.168 us; speedup vs baseline: 1.8331x; 1.0284x over previous
//
#include <hip/hip_runtime.h>
#include <hip/hip_bf16.h>
#include <cstdint>
#include <cstddef>

#define DEVI static __device__ __forceinline__

typedef short s16x8 __attribute__((ext_vector_type(8)));
typedef float f32x4 __attribute__((ext_vector_type(4)));

DEVI f32x4 mfma16x16(s16x8 a, s16x8 b, f32x4 c) {
  return __builtin_amdgcn_mfma_f32_16x16x32_bf16(a, b, c, 0, 0, 0);
}

// HW float->bf16
DEVI unsigned short hcvt(float f) {
  return __builtin_bit_cast(unsigned short, __float2bfloat16(f));
}
DEVI unsigned pk2(float a, float b) {
  return (unsigned)hcvt(a) | ((unsigned)hcvt(b) << 16);
}
// packed cvt: dst[15:0]=bf16(a), dst[31:16]=bf16(b)  (T12 recipe)
DEVI unsigned cvtpk(float a, float b) {
  unsigned r;
  asm("v_cvt_pk_bf16_f32 %0, %1, %2" : "=v"(r) : "v"(a), "v"(b));
  return r;
}

DEVI s16x8 ld8(const unsigned short* p) { return *(const s16x8*)p; }

// async global->LDS, 16B per lane; dest = wave-uniform base + lane*16
DEVI void gload16(const void* g, void* l) {
  __builtin_amdgcn_global_load_lds(
      (const __attribute__((address_space(1))) void*)g,
      (__attribute__((address_space(3))) void*)l, 16, 0, 0);
}

// ---------------------------------------------------------------------------
// fused fp32 -> bf16 bulk convert of all three inputs (one launch)
// ---------------------------------------------------------------------------
__global__ __launch_bounds__(256) void cvt_all(
    const float* __restrict__ x, const float* __restrict__ w1,
    const float* __restrict__ w2, unsigned short* __restrict__ Xb,
    unsigned short* __restrict__ Wb, unsigned short* __restrict__ Wob) {
  int i = blockIdx.x * 256 + threadIdx.x;   // [0, 1048576)
  const float* s;
  unsigned short* d;
  int off;
  if (i < 524288) { s = x; d = Xb; off = i; }
  else if (i < 917504) { s = w1; d = Wb; off = i - 524288; }
  else { s = w2; d = Wob; off = i - 917504; }
  const float4* sp = (const float4*)s + (size_t)off * 2;
  float4 a = sp[0], b = sp[1];
  s16x8 r;
  r[0] = (short)hcvt(a.x); r[1] = (short)hcvt(a.y);
  r[2] = (short)hcvt(a.z); r[3] = (short)hcvt(a.w);
  r[4] = (short)hcvt(b.x); r[5] = (short)hcvt(b.y);
  r[6] = (short)hcvt(b.z); r[7] = (short)hcvt(b.w);
  *(s16x8*)(d + (size_t)off * 8) = r;
}

// ---------------------------------------------------------------------------
// C[m][n] = sum_k A[m][k] * B[n][k]   (NT GEMM, bf16 in, fp32 acc)
// STAGE==1: global_load_lds staging (m97 2-barrier loop), swizzle via
//           pre-swizzled GLOBAL chunk (rule 21): ck = (c&7)^(row&7).
// STAGE==0: reg-staged with in-wave prefetch (for 1-block/CU grids).
// EPI==0: Cf fp32 [M][N].   EPI==2: fused qkv split + RoPE epilogue.
// ---------------------------------------------------------------------------
template <int EPI, int STAGE>
__global__ __launch_bounds__(256, 2) void gemm_nt(
    const unsigned short* __restrict__ A, const unsigned short* __restrict__ B,
    float* __restrict__ Cf, unsigned short* __restrict__ Qp,
    unsigned short* __restrict__ Kp, unsigned short* __restrict__ Vp,
    int M, int N, int K) {
  __shared__ __align__(16) unsigned short As[128 * 64];
  __shared__ __align__(16) unsigned short Bs[128 * 64];
  const int tid = threadIdx.x;
  const int m0 = blockIdx.y * 128, n0 = blockIdx.x * 128;
  const int wid = tid >> 6, lane = tid & 63;
  const int wm = wid >> 1, wn = wid & 1;
  const int lr = lane & 15, lg = lane >> 4;

  f32x4 acc[4][4] = {};
  const int T = K >> 6;

  auto compute_step = [&]() {
    s16x8 af[4][2], bf[4][2];
    #pragma unroll
    for (int m = 0; m < 4; ++m)
      #pragma unroll
      for (int kk = 0; kk < 2; ++kk) {
        int row = wm * 64 + m * 16 + lr;
        af[m][kk] = *(const s16x8*)&As[row * 64 + ((kk * 32 + lg * 8) ^ ((row & 7) << 3))];
      }
    #pragma unroll
    for (int n = 0; n < 4; ++n)
      #pragma unroll
      for (int kk = 0; kk < 2; ++kk) {
        int row = wn * 64 + n * 16 + lr;
        bf[n][kk] = *(const s16x8*)&Bs[row * 64 + ((kk * 32 + lg * 8) ^ ((row & 7) << 3))];
      }
    #pragma unroll
    for (int kk = 0; kk < 2; ++kk)
      #pragma unroll
      for (int m = 0; m < 4; ++m)
        #pragma unroll
        for (int n = 0; n < 4; ++n)
          acc[m][n] = mfma16x16(af[m][kk], bf[n][kk], acc[m][n]);
  };

  if constexpr (STAGE == 1) {
    for (int t = 0; t < T; ++t) {
      const int k0 = t << 6;
      __syncthreads();
      #pragma unroll
      for (int j = 0; j < 4; ++j) {
        const int c = j * 256 + tid;
        const int row = c >> 3;
        const int ck = (c & 7) ^ (row & 7);
        gload16(A + (size_t)(m0 + row) * K + k0 + ck * 8,
                &As[(j * 256 + (tid & 192)) * 8]);
        gload16(B + (size_t)(n0 + row) * K + k0 + ck * 8,
                &Bs[(j * 256 + (tid & 192)) * 8]);
      }
      asm volatile("s_waitcnt vmcnt(0)" ::: "memory");
      __syncthreads();
      compute_step();
    }
  } else {
    s16x8 pa[4], pb[4];
    #pragma unroll
    for (int j = 0; j < 4; ++j) {
      int c = tid + j * 256, row = c >> 3, cc = c & 7;
      pa[j] = ld8(A + (size_t)(m0 + row) * K + cc * 8);
      pb[j] = ld8(B + (size_t)(n0 + row) * K + cc * 8);
    }
    for (int t = 0; t < T; ++t) {
      __syncthreads();
      #pragma unroll
      for (int j = 0; j < 4; ++j) {
        int c = tid + j * 256, row = c >> 3, cc = c & 7;
        int le = row * 64 + ((cc * 8) ^ ((row & 7) << 3));
        *(s16x8*)&As[le] = pa[j];
        *(s16x8*)&Bs[le] = pb[j];
      }
      __syncthreads();
      if (t + 1 < T) {
        const int k0 = (t + 1) << 6;
        #pragma unroll
        for (int j = 0; j < 4; ++j) {
          int c = tid + j * 256, row = c >> 3, cc = c & 7;
          pa[j] = ld8(A + (size_t)(m0 + row) * K + k0 + cc * 8);
          pb[j] = ld8(B + (size_t)(n0 + row) * K + k0 + cc * 8);
        }
      }
      compute_step();
    }
  }

  // epilogue  (C/D layout: row = lg*4 + i, col = lr)
  if constexpr (EPI == 0) {
    #pragma unroll
    for (int m = 0; m < 4; ++m)
      #pragma unroll
      for (int i = 0; i < 4; ++i) {
        int r = m0 + wm * 64 + m * 16 + lg * 4 + i;
        #pragma unroll
        for (int n = 0; n < 4; ++n)
          Cf[(size_t)r * N + n0 + wn * 64 + n * 16 + lr] = acc[m][n][i];
      }
  } else {
    const int colb = n0 + wn * 64;          // wave's 64-col span = one head
    const int part = colb >> 10;            // 0=q 1=k 2=v (block-uniform)
    const int h = (colb & 1023) >> 6;
    #pragma unroll
    for (int m = 0; m < 4; ++m)
      #pragma unroll
      for (int i = 0; i < 4; ++i) {
        const int r = m0 + wm * 64 + m * 16 + lg * 4 + i;
        const int b = r >> 11, s = r & 2047;
        const size_t bh = (size_t)b * 16 + h;
        if (part == 2) {
          #pragma unroll
          for (int n = 0; n < 4; ++n)
            Vp[(bh * 64 + n * 16 + lr) * 2048 + s] = hcvt(acc[m][n][i]);
        } else {
          #pragma unroll
          for (int n = 0; n < 2; ++n) {
            const int d = n * 16 + lr;      // 0..31; pair (d, d+32) in-lane
            float ang = (float)s * exp2f((float)d * -0.4152410118609203f);
            float c = __cosf(ang), sn = __sinf(ang);
            float x1 = acc[m][n][i], x2 = acc[m][n + 2][i];
            float o1 = x1 * c - x2 * sn;
            float o2 = x2 * c + x1 * sn;
            unsigned short* dst;
            if (part == 0) {
              // fold 1/sqrt(dh) AND log2(e) so attention can use exp2
              o1 *= 0.18033688f; o2 *= 0.18033688f; dst = Qp;
            } else dst = Kp;
            dst[(bh * 2048 + s) * 64 + d] = hcvt(o1);
            dst[(bh * 2048 + s) * 64 + d + 32] = hcvt(o2);
          }
        }
      }
  }
}

// ---------------------------------------------------------------------------
// Causal flash attention — swapped softmax, speculative rescale (exact).
// Qr/Kr: bf16 [BH][S][64] (Q pre-scaled by log2e/8), VT: bf16 [BH][64][S],
// Z: bf16 [B*S][1024].
// Block: 2 waves x 16 q-rows; q-tile pair (p, 63-p) -> 33 iters/block.
// Grid: 1024 blocks (XCD-chunked) = 4/CU. K/V dbuf via global_load_lds.
// Critical chain: QK(C-init=-mrun) -> mask -> exp2 -> cvt_pk -> P.lds -> PV.
// Max-tree/shfls/guard run OFF-chain; rare alpha fixup applied AFTER PV
// (exact: O' = a(O + PV(e)), l' = a(l + sum e)).  mrun0 = 0 (|S_log2|<~15,
// e <= 2^15, no overflow; O = sum(eV)/sum(e) is scale-invariant).
// ---------------------------------------------------------------------------
__global__ __launch_bounds__(128, 2) void attn_fwd(
    const unsigned short* __restrict__ Qr, const unsigned short* __restrict__ Kr,
    const unsigned short* __restrict__ VT, unsigned short* __restrict__ Z) {
  __shared__ __align__(16) unsigned short Kl[2][64 * 64];
  __shared__ __align__(16) unsigned short Vl[2][64 * 64];
  __shared__ __align__(16) unsigned short Pl[2][16 * 64];
  const int tid = threadIdx.x;
  const int orig = blockIdx.x;
  const int bid = (orig & 7) * 128 + (orig >> 3);   // XCD-chunked, bijective
  const int bh = bid >> 5, p = bid & 31;
  const int b = bh >> 4, h = bh & 15;
  const int wid = tid >> 6, lane = tid & 63;
  const int lr = lane & 15, lg = lane >> 4;

  const unsigned short* Qb = Qr + ((size_t)bh << 17);
  const unsigned short* Kb = Kr + ((size_t)bh << 17);
  const unsigned short* Vb = VT + ((size_t)bh << 17);

  const int s_row0 = tid >> 3;              // staging rows tid/8 + j*16
  const int s_ck0 = tid & 7;

  #pragma unroll
  for (int side = 0; side < 2; ++side) {
    const int qt = side ? (63 - p) : p;     // 32-row q-tile index
    const int qw = qt * 32 + wid * 16;      // wave's first q row
    const int qabs = qw + lr;               // THE q-row this lane owns
    const int nt = (qt >> 1) + 1;           // KV tiles 0..nt-1

    s16x8 qf[2];
    #pragma unroll
    for (int kk = 0; kk < 2; ++kk)
      qf[kk] = ld8(Qb + (size_t)(qw + lr) * 64 + kk * 32 + lg * 8);

    f32x4 oacc[4] = {};                     // O^T[d = n*16+lg*4+i][q = lr]
    float mrun = 0.f, lrun = 0.f;

    auto STAGE = [&](int buf, int t2) {
      const int kv = t2 << 6;
      #pragma unroll
      for (int j = 0; j < 4; ++j) {
        const int row = s_row0 + j * 16;
        const int ck = s_ck0 ^ (row & 7);
        gload16(Kb + (size_t)(kv + row) * 64 + ck * 8,
                &Kl[buf][(j * 128 + (tid & 64)) * 8]);
        gload16(Vb + (size_t)row * 2048 + kv + ck * 8,
                &Vl[buf][(j * 128 + (tid & 64)) * 8]);
      }
    };

    STAGE(0, 0);
    asm volatile("s_waitcnt vmcnt(0)" ::: "memory");
    __syncthreads();
    int cur = 0;

    for (int t = 0; t < nt; ++t) {
      const int kv0 = t << 6;
      if (t + 1 < nt) STAGE(cur ^ 1, t + 1);   // overlaps all compute below

      // S^T - mrun = K Q^T with C-init = -mrun (swapped operands):
      // sacc[n][i] = S[k = kv0+n*16+lg*4+i][q = qabs] - mrun
      f32x4 cin;
      cin[0] = cin[1] = cin[2] = cin[3] = -mrun;
      f32x4 sacc[4] = {cin, cin, cin, cin};
      __builtin_amdgcn_s_setprio(1);
      #pragma unroll
      for (int kk = 0; kk < 2; ++kk) {
        s16x8 kf[4];
        #pragma unroll
        for (int n = 0; n < 4; ++n) {
          const int row = n * 16 + lr;
          kf[n] = *(const s16x8*)&Kl[cur][row * 64 + ((kk * 32 + lg * 8) ^ ((row & 7) << 3))];
        }
        #pragma unroll
        for (int n = 0; n < 4; ++n)
          sacc[n] = mfma16x16(kf[n], qf[kk], sacc[n]);
      }
      __builtin_amdgcn_s_setprio(0);

      // V fragments: independent of softmax — hoisted above the P fence
      s16x8 vf[2][4];
      #pragma unroll
      for (int kk = 0; kk < 2; ++kk)
        #pragma unroll
        for (int n = 0; n < 4; ++n) {
          const int row = n * 16 + lr;
          vf[kk][n] = *(const s16x8*)&Vl[cur][row * 64 + ((kk * 32 + lg * 8) ^ ((row & 7) << 3))];
        }

      // causal mask (diagonal tile only)
      if (t == nt - 1) {
        #pragma unroll
        for (int n = 0; n < 4; ++n)
          #pragma unroll
          for (int i = 0; i < 4; ++i)
            if (kv0 + n * 16 + lg * 4 + i > qabs) sacc[n][i] = -__builtin_inff();
      }

      // e = exp2(S - mrun) immediately (chain), pack via cvt_pk -> LDS
      float e[4][4];
      float rs = 0.f;
      #pragma unroll
      for (int n = 0; n < 4; ++n) {
        #pragma unroll
        for (int i = 0; i < 4; ++i) e[n][i] = exp2f(sacc[n][i]);
        uint2 u;
        u.x = cvtpk(e[n][0], e[n][1]);
        u.y = cvtpk(e[n][2], e[n][3]);
        *(uint2*)&Pl[wid][lr * 64 + ((n * 16 + lg * 4) ^ ((lr & 7) << 3))] = u;
        rs += (e[n][0] + e[n][1]) + (e[n][2] + e[n][3]);
      }

      // OFF-chain: row max (guard only) + sum reduction across lane group
      float mn[4];
      #pragma unroll
      for (int n = 0; n < 4; ++n)
        mn[n] = fmaxf(fmaxf(sacc[n][0], sacc[n][1]), fmaxf(sacc[n][2], sacc[n][3]));
      float mxr = fmaxf(fmaxf(mn[0], mn[1]), fmaxf(mn[2], mn[3]));
      mxr = fmaxf(mxr, __shfl_xor(mxr, 16));
      mxr = fmaxf(mxr, __shfl_xor(mxr, 32));
      rs += __shfl_xor(rs, 16);
      rs += __shfl_xor(rs, 32);

      // own-wave P writes must land before fragment reads (rule 18)
      asm volatile("s_waitcnt lgkmcnt(0)" ::: "memory");
      __builtin_amdgcn_sched_barrier(0);

      // O^T += V^T P^T : mfma(A=V^T rows d, B=P rows q) -> C[d][q]
      __builtin_amdgcn_s_setprio(1);
      #pragma unroll
      for (int kk = 0; kk < 2; ++kk) {
        s16x8 pf = *(const s16x8*)&Pl[wid][lr * 64 + ((kk * 32 + lg * 8) ^ ((lr & 7) << 3))];
        #pragma unroll
        for (int n = 0; n < 4; ++n)
          oacc[n] = mfma16x16(vf[kk][n], pf, oacc[n]);
      }
      __builtin_amdgcn_s_setprio(0);

      // rare exact fixup AFTER PV: O' = a(O + PVe), l' = a(l + rs)
      if (__any(mxr > 8.f)) {
        const float g = fmaxf(mxr, 0.f);
        const float a = exp2f(-g);
        lrun = (lrun + rs) * a;
        mrun += g;
        #pragma unroll
        for (int n = 0; n < 4; ++n)
          #pragma unroll
          for (int i = 0; i < 4; ++i) oacc[n][i] *= a;
      } else {
        lrun += rs;
      }

      // next tile's loads done + everyone finished reading buf cur
      asm volatile("s_waitcnt vmcnt(0)" ::: "memory");
      __syncthreads();
      cur ^= 1;
    }

    // normalize (lane-uniform) + write Z[b*S+q][h*64+d], 4x dwordx2 per lane
    const float inv = 1.f / lrun;
    const size_t base = ((size_t)b * 2048 + qabs) * 1024 + h * 64;
    #pragma unroll
    for (int n = 0; n < 4; ++n) {
      uint2 u;
      u.x = cvtpk(oacc[n][0] * inv, oacc[n][1] * inv);
      u.y = cvtpk(oacc[n][2] * inv, oacc[n][3] * inv);
      *(uint2*)&Z[base + n * 16 + lg * 4] = u;
    }
  }
}

// ---------------------------------------------------------------------------
extern "C" void kernel_launch(void* const* d_in, const int* in_sizes, int n_in,
                              void* d_out, int out_size, void* d_ws, size_t ws_size,
                              hipStream_t stream) {
  const float* x     = (const float*)d_in[0];   // [2,2048,1024]
  const float* w_qkv = (const float*)d_in[1];   // [3072,1024]
  const float* w_o   = (const float*)d_in[2];   // [1024,1024]
  float* out = (float*)d_out;                   // [2,2048,1024] fp32

  unsigned short* wsp = (unsigned short*)d_ws;
  unsigned short* Qr  = wsp;                    // [32][2048][64] bf16  (8 MB)
  unsigned short* Kr  = wsp + 4194304;          // [32][2048][64] bf16  (8 MB)
  unsigned short* VT  = wsp + 8388608;          // [32][64][2048] bf16  (8 MB)
  unsigned short* Xb  = wsp + 12582912;         // [4096][1024]  bf16   (8 MB)
  unsigned short* Z   = Xb;                     // aliases Xb (disjoint lifetime)
  unsigned short* Wb  = wsp + 16777216;         // [3072][1024]  bf16   (6 MB)
  unsigned short* Wob = wsp + 19922944;         // [1024][1024]  bf16   (2 MB)
  // total ws use: 40 MiB

  // 0) fused one-time fp32 -> bf16 conversions
  cvt_all<<<4096, 256, 0, stream>>>(x, w_qkv, w_o, Xb, Wb, Wob);

  // 1) QKV projection (global_load_lds staging) + fused RoPE epilogue
  gemm_nt<2, 1><<<dim3(24, 32), 256, 0, stream>>>(
      Xb, Wb, nullptr, Qr, Kr, VT, 4096, 3072, 1024);

  // 2) causal flash attention
  attn_fwd<<<1024, 128, 0, stream>>>(Qr, Kr, VT, Z);

  // 3) output projection (reg-staged; 1 block/CU grid) (fp32 out)
  gemm_nt<0, 0><<<dim3(8, 32), 256, 0, stream>>>(
      Z, Wob, out, nullptr, nullptr, nullptr, 4096, 1024, 1024);
}

// Round 7
// 122.918 us; speedup vs baseline: 1.8369x; 1.0020x over previous
//
#include <hip/hip_runtime.h>
#include <hip/hip_bf16.h>
#include <cstdint>
#include <cstddef>

#define DEVI static __device__ __forceinline__

typedef short s16x8 __attribute__((ext_vector_type(8)));
typedef float f32x4 __attribute__((ext_vector_type(4)));
typedef unsigned u32x4 __attribute__((ext_vector_type(4)));

DEVI f32x4 mfma16x16(s16x8 a, s16x8 b, f32x4 c) {
  return __builtin_amdgcn_mfma_f32_16x16x32_bf16(a, b, c, 0, 0, 0);
}

// HW float->bf16
DEVI unsigned short hcvt(float f) {
  return __builtin_bit_cast(unsigned short, __float2bfloat16(f));
}
// packed cvt: dst[15:0]=bf16(a), dst[31:16]=bf16(b)
DEVI unsigned cvtpk(float a, float b) {
  unsigned r;
  asm("v_cvt_pk_bf16_f32 %0, %1, %2" : "=v"(r) : "v"(a), "v"(b));
  return r;
}

DEVI s16x8 ld8(const unsigned short* p) { return *(const s16x8*)p; }

// async global->LDS, 16B per lane; dest = wave-uniform base + lane*16
DEVI void gload16(const void* g, void* l) {
  __builtin_amdgcn_global_load_lds(
      (const __attribute__((address_space(1))) void*)g,
      (__attribute__((address_space(3))) void*)l, 16, 0, 0);
}

// ---------------------------------------------------------------------------
// fused fp32 -> bf16 bulk convert of all three inputs (one launch)
// ---------------------------------------------------------------------------
__global__ __launch_bounds__(256) void cvt_all(
    const float* __restrict__ x, const float* __restrict__ w1,
    const float* __restrict__ w2, unsigned short* __restrict__ Xb,
    unsigned short* __restrict__ Wb, unsigned short* __restrict__ Wob) {
  int i = blockIdx.x * 256 + threadIdx.x;   // [0, 1048576)
  const float* s;
  unsigned short* d;
  int off;
  if (i < 524288) { s = x; d = Xb; off = i; }
  else if (i < 917504) { s = w1; d = Wb; off = i - 524288; }
  else { s = w2; d = Wob; off = i - 917504; }
  const float4* sp = (const float4*)s + (size_t)off * 2;
  float4 a = sp[0], b = sp[1];
  s16x8 r;
  r[0] = (short)hcvt(a.x); r[1] = (short)hcvt(a.y);
  r[2] = (short)hcvt(a.z); r[3] = (short)hcvt(a.w);
  r[4] = (short)hcvt(b.x); r[5] = (short)hcvt(b.y);
  r[6] = (short)hcvt(b.z); r[7] = (short)hcvt(b.w);
  *(s16x8*)(d + (size_t)off * 8) = r;
}

// ---------------------------------------------------------------------------
// GEMM1: C[m][n] = sum_k A[m][k]*B[n][k], 128x128x64 tiles, global_load_lds
// staging (m97 loop, pre-swizzled source chunk), fused qkv/RoPE epilogue.
// XCD-chunked block swizzle (768 blocks % 8 == 0).
// ---------------------------------------------------------------------------
__global__ __launch_bounds__(256, 2) void gemm_qkv(
    const unsigned short* __restrict__ A, const unsigned short* __restrict__ B,
    unsigned short* __restrict__ Qp, unsigned short* __restrict__ Kp,
    unsigned short* __restrict__ Vp, int M, int N, int K) {
  __shared__ __align__(16) unsigned short As[128 * 64];
  __shared__ __align__(16) unsigned short Bs[128 * 64];
  const int tid = threadIdx.x;
  const int lin = blockIdx.y * 24 + blockIdx.x;       // 0..767
  const int swz = (lin & 7) * 96 + (lin >> 3);        // XCD-chunked, bijective
  const int m0 = (swz / 24) * 128, n0 = (swz % 24) * 128;
  const int wid = tid >> 6, lane = tid & 63;
  const int wm = wid >> 1, wn = wid & 1;
  const int lr = lane & 15, lg = lane >> 4;

  f32x4 acc[4][4] = {};
  const int T = K >> 6;

  for (int t = 0; t < T; ++t) {
    const int k0 = t << 6;
    __syncthreads();
    #pragma unroll
    for (int j = 0; j < 4; ++j) {
      const int c = j * 256 + tid;
      const int row = c >> 3;
      const int ck = (c & 7) ^ (row & 7);
      gload16(A + (size_t)(m0 + row) * K + k0 + ck * 8,
              &As[(j * 256 + (tid & 192)) * 8]);
      gload16(B + (size_t)(n0 + row) * K + k0 + ck * 8,
              &Bs[(j * 256 + (tid & 192)) * 8]);
    }
    asm volatile("s_waitcnt vmcnt(0)" ::: "memory");
    __syncthreads();
    s16x8 af[4][2], bf[4][2];
    #pragma unroll
    for (int m = 0; m < 4; ++m)
      #pragma unroll
      for (int kk = 0; kk < 2; ++kk) {
        int row = wm * 64 + m * 16 + lr;
        af[m][kk] = *(const s16x8*)&As[row * 64 + ((kk * 32 + lg * 8) ^ ((row & 7) << 3))];
      }
    #pragma unroll
    for (int n = 0; n < 4; ++n)
      #pragma unroll
      for (int kk = 0; kk < 2; ++kk) {
        int row = wn * 64 + n * 16 + lr;
        bf[n][kk] = *(const s16x8*)&Bs[row * 64 + ((kk * 32 + lg * 8) ^ ((row & 7) << 3))];
      }
    #pragma unroll
    for (int kk = 0; kk < 2; ++kk)
      #pragma unroll
      for (int m = 0; m < 4; ++m)
        #pragma unroll
        for (int n = 0; n < 4; ++n)
          acc[m][n] = mfma16x16(af[m][kk], bf[n][kk], acc[m][n]);
  }

  // fused qkv split + RoPE epilogue (C/D layout: row = lg*4+i, col = lr)
  const int colb = n0 + wn * 64;          // wave's 64-col span = one head
  const int part = colb >> 10;            // 0=q 1=k 2=v (block-uniform)
  const int h = (colb & 1023) >> 6;
  #pragma unroll
  for (int m = 0; m < 4; ++m)
    #pragma unroll
    for (int i = 0; i < 4; ++i) {
      const int r = m0 + wm * 64 + m * 16 + lg * 4 + i;
      const int b = r >> 11, s = r & 2047;
      const size_t bh = (size_t)b * 16 + h;
      if (part == 2) {
        #pragma unroll
        for (int n = 0; n < 4; ++n)
          Vp[(bh * 64 + n * 16 + lr) * 2048 + s] = hcvt(acc[m][n][i]);
      } else {
        #pragma unroll
        for (int n = 0; n < 2; ++n) {
          const int d = n * 16 + lr;      // 0..31; pair (d, d+32) in-lane
          float ang = (float)s * exp2f((float)d * -0.4152410118609203f);
          float c = __cosf(ang), sn = __sinf(ang);
          float x1 = acc[m][n][i], x2 = acc[m][n + 2][i];
          float o1 = x1 * c - x2 * sn;
          float o2 = x2 * c + x1 * sn;
          unsigned short* dst;
          if (part == 0) {
            // fold 1/sqrt(dh) AND log2(e) so attention can use exp2
            o1 *= 0.18033688f; o2 *= 0.18033688f; dst = Qp;
          } else dst = Kp;
          dst[(bh * 2048 + s) * 64 + d] = hcvt(o1);
          dst[(bh * 2048 + s) * 64 + d + 32] = hcvt(o2);
        }
      }
    }
}

// ---------------------------------------------------------------------------
// GEMM3: 128x64 tiles (2 blocks/CU), global_load_lds staging, fp32 out.
// 4 waves, each 32 rows x 64 cols (acc[2][4]). XCD-chunked swizzle.
// ---------------------------------------------------------------------------
__global__ __launch_bounds__(256, 2) void gemm_out(
    const unsigned short* __restrict__ A, const unsigned short* __restrict__ B,
    float* __restrict__ Cf, int M, int N, int K) {
  __shared__ __align__(16) unsigned short As[128 * 64];
  __shared__ __align__(16) unsigned short Bs[64 * 64];
  const int tid = threadIdx.x;
  const int lin = blockIdx.y * 16 + blockIdx.x;       // 0..511
  const int swz = (lin & 7) * 64 + (lin >> 3);        // XCD-chunked, bijective
  const int m0 = (swz >> 4) * 128, n0 = (swz & 15) * 64;
  const int wid = tid >> 6, lane = tid & 63;
  const int lr = lane & 15, lg = lane >> 4;

  f32x4 acc[2][4] = {};
  const int T = K >> 6;

  for (int t = 0; t < T; ++t) {
    const int k0 = t << 6;
    __syncthreads();
    #pragma unroll
    for (int j = 0; j < 4; ++j) {
      const int c = j * 256 + tid;
      const int row = c >> 3;
      const int ck = (c & 7) ^ (row & 7);
      gload16(A + (size_t)(m0 + row) * K + k0 + ck * 8,
              &As[(j * 256 + (tid & 192)) * 8]);
    }
    #pragma unroll
    for (int j = 0; j < 2; ++j) {
      const int c = j * 256 + tid;
      const int row = c >> 3;
      const int ck = (c & 7) ^ (row & 7);
      gload16(B + (size_t)(n0 + row) * K + k0 + ck * 8,
              &Bs[(j * 256 + (tid & 192)) * 8]);
    }
    asm volatile("s_waitcnt vmcnt(0)" ::: "memory");
    __syncthreads();
    s16x8 af[2][2], bf[4][2];
    #pragma unroll
    for (int m = 0; m < 2; ++m)
      #pragma unroll
      for (int kk = 0; kk < 2; ++kk) {
        int row = wid * 32 + m * 16 + lr;
        af[m][kk] = *(const s16x8*)&As[row * 64 + ((kk * 32 + lg * 8) ^ ((row & 7) << 3))];
      }
    #pragma unroll
    for (int n = 0; n < 4; ++n)
      #pragma unroll
      for (int kk = 0; kk < 2; ++kk) {
        int row = n * 16 + lr;
        bf[n][kk] = *(const s16x8*)&Bs[row * 64 + ((kk * 32 + lg * 8) ^ ((row & 7) << 3))];
      }
    #pragma unroll
    for (int kk = 0; kk < 2; ++kk)
      #pragma unroll
      for (int m = 0; m < 2; ++m)
        #pragma unroll
        for (int n = 0; n < 4; ++n)
          acc[m][n] = mfma16x16(af[m][kk], bf[n][kk], acc[m][n]);
  }

  #pragma unroll
  for (int m = 0; m < 2; ++m)
    #pragma unroll
    for (int i = 0; i < 4; ++i) {
      int r = m0 + wid * 32 + m * 16 + lg * 4 + i;
      #pragma unroll
      for (int n = 0; n < 4; ++n)
        Cf[(size_t)r * N + n0 + n * 16 + lr] = acc[m][n][i];
    }
}

// ---------------------------------------------------------------------------
// Causal flash attention — swapped softmax, zero-shuffle PV via K-row
// permutation sigma, speculative rescale (exact).
// sigma(a) = bit-perm [b4|b3b2|b5|b1b0]: staged K row r holds global K row
// kv0+sigma(r); then the QK C-slot (lg,n,i) IS the PV B-frag slot, so P
// never leaves registers (no LDS round-trip, no lgkm drain). V stays in
// natural order (sigma chosen so sigma(a(k_idx)) == k_idx).
// Qr/Kr: bf16 [BH][S][64] (Q pre-scaled by log2e/8), VT: bf16 [BH][64][S],
// Z: bf16 [B*S][1024].
// Block: 2 waves x 16 q-rows; pair (p, 63-p) -> 33 iters. Grid 1024 = 4/CU.
// ---------------------------------------------------------------------------
__global__ __launch_bounds__(128, 2) void attn_fwd(
    const unsigned short* __restrict__ Qr, const unsigned short* __restrict__ Kr,
    const unsigned short* __restrict__ VT, unsigned short* __restrict__ Z) {
  __shared__ __align__(16) unsigned short Kl[2][64 * 64];
  __shared__ __align__(16) unsigned short Vl[2][64 * 64];
  const int tid = threadIdx.x;
  const int orig = blockIdx.x;
  const int bid = (orig & 7) * 128 + (orig >> 3);   // XCD-chunked, bijective
  const int bh = bid >> 5, p = bid & 31;
  const int b = bh >> 4, h = bh & 15;
  const int wid = tid >> 6, lane = tid & 63;
  const int lr = lane & 15, lg = lane >> 4;

  const unsigned short* Qb = Qr + ((size_t)bh << 17);
  const unsigned short* Kb = Kr + ((size_t)bh << 17);
  const unsigned short* Vb = VT + ((size_t)bh << 17);

  const int s_row0 = tid >> 3;              // staging rows: r = s_row0 + j*16
  const int s_ck0 = tid & 7;

  #pragma unroll
  for (int side = 0; side < 2; ++side) {
    const int qt = side ? (63 - p) : p;     // 32-row q-tile index
    const int qw = qt * 32 + wid * 16;      // wave's first q row
    const int qabs = qw + lr;               // THE q-row this lane owns
    const int nt = (qt >> 1) + 1;           // KV tiles 0..nt-1

    s16x8 qf[2];
    #pragma unroll
    for (int kk = 0; kk < 2; ++kk)
      qf[kk] = ld8(Qb + (size_t)(qw + lr) * 64 + kk * 32 + lg * 8);

    f32x4 oacc[4] = {};                     // O^T[d = n*16+lg*4+i][q = lr]
    float mrun = 0.f, lrun = 0.f;

    // K staged with sigma-permuted source row; V natural.
    // r = j*16 + s_row0; sigma(r) = (j&1)*32 + (s_row0>>2)*8 + (j>>1)*4 + (s_row0&3)
    auto STAGE = [&](int buf, int t2) {
      const int kv = t2 << 6;
      #pragma unroll
      for (int j = 0; j < 4; ++j) {
        const int row = s_row0 + j * 16;
        const int ck = s_ck0 ^ (row & 7);
        const int gk = (j & 1) * 32 + (s_row0 >> 2) * 8 + ((j >> 1) << 2) + (s_row0 & 3);
        gload16(Kb + (size_t)(kv + gk) * 64 + ck * 8,
                &Kl[buf][(j * 128 + (tid & 64)) * 8]);
        gload16(Vb + (size_t)row * 2048 + kv + ck * 8,
                &Vl[buf][(j * 128 + (tid & 64)) * 8]);
      }
    };

    STAGE(0, 0);
    asm volatile("s_waitcnt vmcnt(0)" ::: "memory");
    __syncthreads();
    int cur = 0;

    for (int t = 0; t < nt; ++t) {
      const int kv0 = t << 6;
      if (t + 1 < nt) STAGE(cur ^ 1, t + 1);   // overlaps all compute below

      // S^T - mrun = K Q^T with C-init = -mrun (swapped operands)
      // sacc[n][i] = S[k_global = kv0 + sigma(n*16+lg*4+i)][q = qabs] - mrun
      f32x4 cin;
      cin[0] = cin[1] = cin[2] = cin[3] = -mrun;
      f32x4 sacc[4] = {cin, cin, cin, cin};
      __builtin_amdgcn_s_setprio(1);
      #pragma unroll
      for (int kk = 0; kk < 2; ++kk) {
        s16x8 kf[4];
        #pragma unroll
        for (int n = 0; n < 4; ++n) {
          const int row = n * 16 + lr;
          kf[n] = *(const s16x8*)&Kl[cur][row * 64 + ((kk * 32 + lg * 8) ^ ((row & 7) << 3))];
        }
        #pragma unroll
        for (int n = 0; n < 4; ++n)
          sacc[n] = mfma16x16(kf[n], qf[kk], sacc[n]);
      }
      __builtin_amdgcn_s_setprio(0);

      // V fragments (independent of softmax)
      s16x8 vf[2][4];
      #pragma unroll
      for (int kk = 0; kk < 2; ++kk)
        #pragma unroll
        for (int n = 0; n < 4; ++n) {
          const int row = n * 16 + lr;
          vf[kk][n] = *(const s16x8*)&Vl[cur][row * 64 + ((kk * 32 + lg * 8) ^ ((row & 7) << 3))];
        }

      // causal mask (diagonal tile only), sigma-mapped k per slot
      if (t == nt - 1) {
        #pragma unroll
        for (int n = 0; n < 4; ++n)
          #pragma unroll
          for (int i = 0; i < 4; ++i)
            if (kv0 + (n & 1) * 32 + lg * 8 + ((n >> 1) << 2) + i > qabs)
              sacc[n][i] = -__builtin_inff();
      }

      // e = exp2(S - mrun) (chain), P-frags built IN REGISTERS:
      // pf[f] words = {cvtpk(e[f][0],e[f][1]), cvtpk(e[f][2],e[f][3]),
      //                cvtpk(e[f+2][0],e[f+2][1]), cvtpk(e[f+2][2],e[f+2][3])}
      float e[4][4];
      #pragma unroll
      for (int n = 0; n < 4; ++n)
        #pragma unroll
        for (int i = 0; i < 4; ++i) e[n][i] = exp2f(sacc[n][i]);
      u32x4 u0, u1;
      u0[0] = cvtpk(e[0][0], e[0][1]); u0[1] = cvtpk(e[0][2], e[0][3]);
      u0[2] = cvtpk(e[2][0], e[2][1]); u0[3] = cvtpk(e[2][2], e[2][3]);
      u1[0] = cvtpk(e[1][0], e[1][1]); u1[1] = cvtpk(e[1][2], e[1][3]);
      u1[2] = cvtpk(e[3][0], e[3][1]); u1[3] = cvtpk(e[3][2], e[3][3]);
      s16x8 pf0 = __builtin_bit_cast(s16x8, u0);
      s16x8 pf1 = __builtin_bit_cast(s16x8, u1);

      // OFF-chain reductions (guard max + row sum over the 4 lanes sharing q)
      float rs = 0.f;
      #pragma unroll
      for (int n = 0; n < 4; ++n)
        rs += (e[n][0] + e[n][1]) + (e[n][2] + e[n][3]);
      float mn[4];
      #pragma unroll
      for (int n = 0; n < 4; ++n)
        mn[n] = fmaxf(fmaxf(sacc[n][0], sacc[n][1]), fmaxf(sacc[n][2], sacc[n][3]));
      float mxr = fmaxf(fmaxf(mn[0], mn[1]), fmaxf(mn[2], mn[3]));
      mxr = fmaxf(mxr, __shfl_xor(mxr, 16));
      mxr = fmaxf(mxr, __shfl_xor(mxr, 32));
      rs += __shfl_xor(rs, 16);
      rs += __shfl_xor(rs, 32);

      // O^T += V^T P^T : zero-shuffle PV, P straight from registers
      __builtin_amdgcn_s_setprio(1);
      #pragma unroll
      for (int n = 0; n < 4; ++n)
        oacc[n] = mfma16x16(vf[0][n], pf0, oacc[n]);
      #pragma unroll
      for (int n = 0; n < 4; ++n)
        oacc[n] = mfma16x16(vf[1][n], pf1, oacc[n]);
      __builtin_amdgcn_s_setprio(0);

      // rare exact fixup AFTER PV: O' = a(O + PVe), l' = a(l + rs)
      if (__any(mxr > 8.f)) {
        const float g = fmaxf(mxr, 0.f);
        const float a = exp2f(-g);
        lrun = (lrun + rs) * a;
        mrun += g;
        #pragma unroll
        for (int n = 0; n < 4; ++n)
          #pragma unroll
          for (int i = 0; i < 4; ++i) oacc[n][i] *= a;
      } else {
        lrun += rs;
      }

      // next tile's loads done + everyone finished reading buf cur
      asm volatile("s_waitcnt vmcnt(0)" ::: "memory");
      __syncthreads();
      cur ^= 1;
    }

    // normalize (lane-uniform) + write Z[b*S+q][h*64+d], 4x dwordx2 per lane
    const float inv = 1.f / lrun;
    const size_t base = ((size_t)b * 2048 + qabs) * 1024 + h * 64;
    #pragma unroll
    for (int n = 0; n < 4; ++n) {
      uint2 u;
      u.x = cvtpk(oacc[n][0] * inv, oacc[n][1] * inv);
      u.y = cvtpk(oacc[n][2] * inv, oacc[n][3] * inv);
      *(uint2*)&Z[base + n * 16 + lg * 4] = u;
    }
  }
}

// ---------------------------------------------------------------------------
extern "C" void kernel_launch(void* const* d_in, const int* in_sizes, int n_in,
                              void* d_out, int out_size, void* d_ws, size_t ws_size,
                              hipStream_t stream) {
  const float* x     = (const float*)d_in[0];   // [2,2048,1024]
  const float* w_qkv = (const float*)d_in[1];   // [3072,1024]
  const float* w_o   = (const float*)d_in[2];   // [1024,1024]
  float* out = (float*)d_out;                   // [2,2048,1024] fp32

  unsigned short* wsp = (unsigned short*)d_ws;
  unsigned short* Qr  = wsp;                    // [32][2048][64] bf16  (8 MB)
  unsigned short* Kr  = wsp + 4194304;          // [32][2048][64] bf16  (8 MB)
  unsigned short* VT  = wsp + 8388608;          // [32][64][2048] bf16  (8 MB)
  unsigned short* Xb  = wsp + 12582912;         // [4096][1024]  bf16   (8 MB)
  unsigned short* Z   = Xb;                     // aliases Xb (disjoint lifetime)
  unsigned short* Wb  = wsp + 16777216;         // [3072][1024]  bf16   (6 MB)
  unsigned short* Wob = wsp + 19922944;         // [1024][1024]  bf16   (2 MB)
  // total ws use: 40 MiB

  // 0) fused one-time fp32 -> bf16 conversions
  cvt_all<<<4096, 256, 0, stream>>>(x, w_qkv, w_o, Xb, Wb, Wob);

  // 1) QKV projection (global_load_lds staging) + fused RoPE epilogue
  gemm_qkv<<<dim3(24, 32), 256, 0, stream>>>(
      Xb, Wb, Qr, Kr, VT, 4096, 3072, 1024);

  // 2) causal flash attention (zero-shuffle PV)
  attn_fwd<<<1024, 128, 0, stream>>>(Qr, Kr, VT, Z);

  // 3) output projection (128x64 tiles, 2 blocks/CU) (fp32 out)
  gemm_out<<<dim3(16, 32), 256, 0, stream>>>(
      Z, Wob, out, 4096, 1024, 1024);
}